// Round 16
// baseline (11462.935 us; speedup 1.0000x reference)
//
#include <hip/hip_runtime.h>
#include <hip/hip_bf16.h>
#include <cstddef>

// ---------------- problem constants ----------------
constexpr int B_ = 64, T_ = 512, E_ = 768, H_ = 512, G_ = 1536, NF_ = 256;

typedef float f32x4 __attribute__((ext_vector_type(4)));
typedef __bf16 bf16x8 __attribute__((ext_vector_type(8)));

// ---------------- workspace layout (bytes) ----------------
// Phase SEL: [0,50.3MB) gi ring (f32, depth 128 t) | [64MB,160MB) giFull bf16
//            [160MB,~170MB) bf16 weights | >=192MB control/h as before.
// Phase REC: [0,64MB) out1 f32 (ring dead) | giFull + weights live.
constexpr size_t OFF_RING_GI = 0;                            // 64*128*1536*4 = 50.3MB
constexpr size_t OFF_OUT     = 0;                            // out1 f32 64MB (post-sel)
constexpr size_t OFF_GIFULL  = 64ull * 1024 * 1024;          // 96MB bf16
constexpr size_t OFF_WBF0    = 160ull * 1024 * 1024;
constexpr size_t OFF_WBF1 = OFF_WBF0 + (size_t)G_ * H_ * 2;
constexpr size_t OFF_WIH0 = OFF_WBF1 + (size_t)G_ * H_ * 2;  // kept for layout compat (unused)
constexpr size_t OFF_WIH1 = OFF_WIH0 + (size_t)G_ * E_ * 2;
constexpr size_t OFF_WC3  = OFF_WIH1 + (size_t)G_ * H_ * 2;
constexpr size_t OFF_WC4  = OFF_WC3 + (size_t)NF_ * 3 * H_ * 2;
constexpr size_t OFF_WC5  = OFF_WC4 + (size_t)NF_ * 4 * H_ * 2;
constexpr size_t OFF_MISC = 192ull * 1024 * 1024;
constexpr size_t OFF_H0   = OFF_MISC;                        // 256KB
constexpr size_t OFF_H1   = OFF_H0 + (size_t)B_ * H_ * 4;
constexpr size_t OFF_SEL  = OFF_H1 + (size_t)B_ * H_ * 4;    // uint64 selm[T_]
constexpr size_t OFF_ORD  = OFF_SEL + (size_t)B_ * T_ * 4;
constexpr size_t OFF_NSEL = OFF_ORD + (size_t)B_ * T_ * 4;
constexpr size_t OFF_MAXN = OFF_NSEL + 256;
constexpr size_t OFF_FLG  = OFF_MAXN + 256;   // sel flags[128] / fused A,B,C
constexpr size_t OFF_JOBS = OFF_FLG + 512;    // jobs_done[8]
constexpr size_t OFF_POOL = OFF_FLG + 1024;
constexpr size_t OFF_RING0 = OFF_POOL + (size_t)B_ * 3 * NF_ * 4;   // out0 ring [4][64][512] bf16
constexpr size_t OFF_RING1 = OFF_RING0 + 4ull * 64 * 512 * 2;       // gi1 ring [4][64][1536] bf16
constexpr size_t WS_NEED  = OFF_RING1 + 4ull * 64 * 1536 * 2;

// merged weight-prep region sizes (elements)
constexpr int WP_N0 = G_ * H_;
constexpr int WP_N1 = WP_N0 + G_ * H_;
constexpr int WP_N2 = WP_N1 + G_ * E_;
constexpr int WP_N3 = WP_N2 + G_ * H_;
constexpr int WP_N4 = WP_N3 + NF_ * 3 * H_;
constexpr int WP_N5 = WP_N4 + NF_ * 4 * H_;
constexpr int WP_N6 = WP_N5 + NF_ * 5 * H_;

// coherent (fabric-level, L1/L2-bypass) access helpers
#define CLOAD4(dst, ptr) \
    asm volatile("global_load_dwordx4 %0, %1, off sc0 sc1" : "=v"(dst) : "v"(ptr))
#define CLOAD2(dst, ptr) \
    asm volatile("global_load_dwordx2 %0, %1, off sc0 sc1" : "=v"(dst) : "v"(ptr))
#define CWAIT() do { \
    asm volatile("s_waitcnt vmcnt(0)" ::: "memory"); \
    __builtin_amdgcn_sched_barrier(0); } while (0)
#define CSTORE4(ptr, val) \
    asm volatile("global_store_dword %0, %1, off sc0 sc1" :: "v"(ptr), "v"(val) : "memory")
#define CSTORE8(ptr, val) \
    asm volatile("global_store_dwordx2 %0, %1, off sc0 sc1" :: "v"(ptr), "v"(val) : "memory")
#define CSTORE2(ptr, val) \
    asm volatile("global_store_short %0, %1, off sc0 sc1" :: "v"(ptr), "v"(val) : "memory")
#define CSTOREX4(ptr, val) \
    asm volatile("global_store_dwordx4 %0, %1, off sc0 sc1" :: "v"(ptr), "v"(val) : "memory")

__device__ __forceinline__ float sigm(float x) { return 1.f / (1.f + expf(-x)); }
__device__ __forceinline__ float b2f(unsigned short u) {
    return __uint_as_float(((unsigned int)u) << 16);
}
__device__ __forceinline__ unsigned short f2bu(float x) {
    __hip_bfloat16 h = __float2bfloat16(x);
    return *(unsigned short*)&h;
}

template<int NWG>
__device__ __forceinline__ void bar_wait(const int* flags, int t, int tid) {
    if (tid < 64) {
        int v;
        for (;;) {
            asm volatile("global_load_dword %0, %1, off sc0 sc1\n\t"
                         "s_waitcnt vmcnt(0)"
                         : "=v"(v) : "v"(flags + (tid & (NWG - 1))) : "memory");
            if (__all(v >= t)) break;
            __builtin_amdgcn_s_sleep(1);
        }
    }
    __syncthreads();
}

// poll first N flags until all >= thresh
template<int N>
__device__ __forceinline__ void poll_ge(const int* flags, int thresh, int tid) {
    if (tid < 64) {
        const int idx = (tid < N) ? tid : 0;
        int v;
        for (;;) {
            asm volatile("global_load_dword %0, %1, off sc0 sc1\n\t"
                         "s_waitcnt vmcnt(0)"
                         : "=v"(v) : "v"(flags + idx) : "memory");
            if (__all(v >= thresh)) break;
            __builtin_amdgcn_s_sleep(1);
        }
    }
    __syncthreads();
}

// per-wave spin on a single counter (all lanes same address)
__device__ __forceinline__ void poll_cnt(const int* p, int thr) {
    int v;
    for (;;) {
        asm volatile("global_load_dword %0, %1, off sc0 sc1\n\t"
                     "s_waitcnt vmcnt(0)"
                     : "=v"(v) : "v"(p) : "memory");
        if (__all(v >= thr)) break;
        __builtin_amdgcn_s_sleep(1);
    }
}

// poll 128 flags (2 per lane) until all >= thr; full-WG sync after
__device__ __forceinline__ void poll128_ge(const int* flags, int thr, int tid) {
    if (tid < 64) {
        int v1, v2;
        for (;;) {
            asm volatile("global_load_dword %0, %2, off sc0 sc1\n\t"
                         "global_load_dword %1, %3, off sc0 sc1\n\t"
                         "s_waitcnt vmcnt(0)"
                         : "=&v"(v1), "=&v"(v2)
                         : "v"(flags + tid), "v"(flags + tid + 64) : "memory");
            if (__all((v1 >= thr) && (v2 >= thr))) break;
            __builtin_amdgcn_s_sleep(1);
        }
    }
    __syncthreads();
}

__device__ __forceinline__ void bar_wait128(const int* flags, int t, int tid) {
    poll128_ge(flags, t, tid);
}

__device__ __forceinline__ void bar_arrive(int* flags, int t, int tid, int idx) {
    asm volatile("s_waitcnt vmcnt(0)" ::: "memory");
    __syncthreads();
    if (tid == 0) { int pv = t + 1; CSTORE4(flags + idx, pv); }
}

// =====================================================================
// bf16 MFMA GEMM (verified r6/r12) — used for the convs.
// =====================================================================
template<int AMODE, int OMODE>
__global__ __launch_bounds__(256) void gemm_mfma(
    const float* __restrict__ A, const unsigned short* __restrict__ Wb,
    const float* __restrict__ bias,
    unsigned short* __restrict__ Cb, unsigned int* __restrict__ pool,
    int N, int K, int ldA, int rowsPerB, int tilesPerB, int nb,
    const int* __restrict__ order, const int* __restrict__ nsel, int poolOff)
{
    __shared__ __align__(16) unsigned short As[64][40];
    __shared__ __align__(16) unsigned short Bs[64][40];
    __shared__ const float* rowp[64];

    const int tid = threadIdx.x;
    const int l = tid & 63;
    const int q = tid >> 6;
    const int per = 16 * nb;
    const int id = blockIdx.x;
    const int sup = id / per, rr2 = id % per;
    const int mblk = sup * 16 + (rr2 & 15);
    const int n0 = (rr2 >> 4) * 64;

    int tileb = 0, tilet0 = 0;
    if (AMODE != 0) { tileb = mblk / tilesPerB; tilet0 = (mblk % tilesPerB) * 64; }

    if (tid < 64) {
        const float* p = nullptr;
        if (AMODE == 0) {
            p = A + ((size_t)mblk * 64 + tid) * (size_t)ldA;
        } else {
            int t = tilet0 + tid;
            if (t < rowsPerB) p = A + ((size_t)tileb * T_ + t) * (size_t)ldA;
        }
        rowp[tid] = p;
    }
    __syncthreads();

    f32x4 acc0 = {0.f,0.f,0.f,0.f}, acc1 = {0.f,0.f,0.f,0.f};
    f32x4 acc2 = {0.f,0.f,0.f,0.f}, acc3 = {0.f,0.f,0.f,0.f};

    const int r = tid & 63, seg = tid >> 6;
    const float* ap = rowp[r];
    if (ap) ap += seg * 8;
    const unsigned short* wrow = Wb + (size_t)(n0 + r) * (size_t)K + seg * 8;

    for (int k0 = 0; k0 < K; k0 += 32) {
        float4 fa = make_float4(0,0,0,0), fb = make_float4(0,0,0,0);
        if (ap) { fa = *(const float4*)(ap + k0); fb = *(const float4*)(ap + k0 + 4); }
        const uint4 wv = *(const uint4*)(wrow + k0);
        __syncthreads();
        uint4 pk;
        pk.x = (unsigned)f2bu(fa.x) | ((unsigned)f2bu(fa.y) << 16);
        pk.y = (unsigned)f2bu(fa.z) | ((unsigned)f2bu(fa.w) << 16);
        pk.z = (unsigned)f2bu(fb.x) | ((unsigned)f2bu(fb.y) << 16);
        pk.w = (unsigned)f2bu(fb.z) | ((unsigned)f2bu(fb.w) << 16);
        *(uint4*)&As[r][seg * 8] = pk;
        *(uint4*)&Bs[r][seg * 8] = wv;
        __syncthreads();
        const bf16x8 av = *(const bf16x8*)&As[q * 16 + (l & 15)][(l >> 4) * 8];
        const bf16x8 b0 = *(const bf16x8*)&Bs[ 0 + (l & 15)][(l >> 4) * 8];
        const bf16x8 b1 = *(const bf16x8*)&Bs[16 + (l & 15)][(l >> 4) * 8];
        const bf16x8 b2 = *(const bf16x8*)&Bs[32 + (l & 15)][(l >> 4) * 8];
        const bf16x8 b3 = *(const bf16x8*)&Bs[48 + (l & 15)][(l >> 4) * 8];
        acc0 = __builtin_amdgcn_mfma_f32_16x16x32_bf16(av, b0, acc0, 0, 0, 0);
        acc1 = __builtin_amdgcn_mfma_f32_16x16x32_bf16(av, b1, acc1, 0, 0, 0);
        acc2 = __builtin_amdgcn_mfma_f32_16x16x32_bf16(av, b2, acc2, 0, 0, 0);
        acc3 = __builtin_amdgcn_mfma_f32_16x16x32_bf16(av, b3, acc3, 0, 0, 0);
    }

    f32x4 accs[4] = {acc0, acc1, acc2, acc3};
    if (OMODE == 0) {
        const int mbase = (AMODE == 0) ? mblk * 64 : tileb * T_ + tilet0;
        #pragma unroll
        for (int s = 0; s < 4; ++s) {
            const int col = n0 + s * 16 + (l & 15);
            const float bv = bias[col];
            #pragma unroll
            for (int reg = 0; reg < 4; ++reg) {
                const int m = mbase + q * 16 + (l >> 4) * 4 + reg;
                Cb[(size_t)m * (size_t)N + col] = f2bu(accs[s][reg] + bv);
            }
        }
    } else {
        #pragma unroll
        for (int s = 0; s < 4; ++s) {
            const int col = n0 + s * 16 + (l & 15);
            const float bv = bias[col];
            float mx = 0.f;
            #pragma unroll
            for (int reg = 0; reg < 4; ++reg) {
                const int t = tilet0 + q * 16 + (l >> 4) * 4 + reg;
                const float val = fmaxf(accs[s][reg] + bv, 0.f);
                if (t < rowsPerB) mx = fmaxf(mx, val);
            }
            mx = fmaxf(mx, __shfl_xor(mx, 16));
            mx = fmaxf(mx, __shfl_xor(mx, 32));
            if (l < 16)
                atomicMax(&pool[(size_t)tileb * (3*NF_) + poolOff + n0 + s*16 + l],
                          __float_as_uint(mx));
        }
    }
}

// =====================================================================
// Producer 64x64 fp32 GEMM job (512 thr). TORING: coherent f32 out to
// the gi ring (k-ascending fma chains + bias-at-store bit-identical to
// the r10-r15 gemm_f32). Else: normal bf16 store to giFull.
// =====================================================================
template<bool TORING>
__device__ __forceinline__ void prod_job(
    int mblk, int n0, int ringRowBase,
    const float* __restrict__ emb, const float* __restrict__ W,
    const float* __restrict__ bias,
    float* __restrict__ ring, unsigned short* __restrict__ full,
    float* As, float* Bs, int tid)
{
    const int half = tid >> 8;
    const int t2 = tid & 255;
    const int srl = t2 >> 2, skl = (t2 & 3) * 4;
    const int ty = tid >> 4, tx = tid & 15;
    const float* src = (half == 0)
        ? emb + ((size_t)mblk * 64 + srl) * (size_t)E_ + skl
        : W + ((size_t)(n0 + srl)) * (size_t)E_ + skl;
    float* dl = (half == 0) ? As : Bs;

    float acc[2][4] = {};
    for (int k0 = 0; k0 < E_; k0 += 16) {
        const float4 v = *(const float4*)(src + k0);
        __syncthreads();
        dl[(skl+0)*68 + srl] = v.x; dl[(skl+1)*68 + srl] = v.y;
        dl[(skl+2)*68 + srl] = v.z; dl[(skl+3)*68 + srl] = v.w;
        __syncthreads();
        #pragma unroll
        for (int kk = 0; kk < 16; ++kk) {
            const float a0 = As[kk*68 + ty*2 + 0];
            const float a1 = As[kk*68 + ty*2 + 1];
            const float4 w4 = *(const float4*)&Bs[kk*68 + tx*4];
            acc[0][0]=fmaf(a0,w4.x,acc[0][0]); acc[0][1]=fmaf(a0,w4.y,acc[0][1]);
            acc[0][2]=fmaf(a0,w4.z,acc[0][2]); acc[0][3]=fmaf(a0,w4.w,acc[0][3]);
            acc[1][0]=fmaf(a1,w4.x,acc[1][0]); acc[1][1]=fmaf(a1,w4.y,acc[1][1]);
            acc[1][2]=fmaf(a1,w4.z,acc[1][2]); acc[1][3]=fmaf(a1,w4.w,acc[1][3]);
        }
    }
    const float4 bv = *(const float4*)(bias + n0 + tx*4);
    if (TORING) {
        f32x4 o0, o1;
        o0[0] = acc[0][0]+bv.x; o0[1] = acc[0][1]+bv.y;
        o0[2] = acc[0][2]+bv.z; o0[3] = acc[0][3]+bv.w;
        o1[0] = acc[1][0]+bv.x; o1[1] = acc[1][1]+bv.y;
        o1[2] = acc[1][2]+bv.z; o1[3] = acc[1][3]+bv.w;
        const float* d0 = ring + (size_t)(ringRowBase + ty*2) * (size_t)G_ + n0 + tx*4;
        CSTOREX4(d0, o0);
        CSTOREX4(d0 + G_, o1);
    } else {
        ushort4 s0, s1;
        s0.x = f2bu(acc[0][0]+bv.x); s0.y = f2bu(acc[0][1]+bv.y);
        s0.z = f2bu(acc[0][2]+bv.z); s0.w = f2bu(acc[0][3]+bv.w);
        s1.x = f2bu(acc[1][0]+bv.x); s1.y = f2bu(acc[1][1]+bv.y);
        s1.z = f2bu(acc[1][2]+bv.z); s1.w = f2bu(acc[1][3]+bv.w);
        unsigned short* d0 = full + (size_t)(mblk * 64 + ty*2) * (size_t)G_ + n0 + tx*4;
        *(ushort4*)d0 = s0;
        *(ushort4*)(d0 + G_) = s1;
    }
}

__device__ __forceinline__ void gates_abs(
    const float* __restrict__ hs, int b, int base,
    const float* __restrict__ wR, const float* __restrict__ wZ,
    const float* __restrict__ wN,
    float& aR, float& aZ, float& aN)
{
    #pragma unroll 4
    for (int kq = 0; kq < 32; ++kq) {
        const int k = base + kq * 4;
        const float hv0 = hs[(k+0)*64 + b];
        const float hv1 = hs[(k+1)*64 + b];
        const float hv2 = hs[(k+2)*64 + b];
        const float hv3 = hs[(k+3)*64 + b];
        const float4 wr = *(const float4*)(wR + k);
        const float4 wz = *(const float4*)(wZ + k);
        const float4 wn = *(const float4*)(wN + k);
        aR = fmaf(hv0, wr.x, aR); aR = fmaf(hv1, wr.y, aR);
        aR = fmaf(hv2, wr.z, aR); aR = fmaf(hv3, wr.w, aR);
        aZ = fmaf(hv0, wz.x, aZ); aZ = fmaf(hv1, wz.y, aZ);
        aZ = fmaf(hv2, wz.z, aZ); aZ = fmaf(hv3, wz.w, aZ);
        aN = fmaf(hv0, wn.x, aN); aN = fmaf(hv1, wn.y, aN);
        aN = fmaf(hv2, wn.z, aN); aN = fmaf(hv3, wn.w, aN);
    }
}

__device__ __forceinline__ void dot_abs(
    const float* __restrict__ hs, int b, int base,
    const float* __restrict__ dWl, float& dot)
{
    #pragma unroll 4
    for (int kq = 0; kq < 16; ++kq) {
        const int k = base + kq * 4;
        const float hv0 = hs[(k+0)*64 + b];
        const float hv1 = hs[(k+1)*64 + b];
        const float hv2 = hs[(k+2)*64 + b];
        const float hv3 = hs[(k+3)*64 + b];
        const float4 dv = *(const float4*)(dWl + k);
        dot = fmaf(hv0, dv.x, dot); dot = fmaf(hv1, dv.y, dot);
        dot = fmaf(hv2, dv.z, dot); dot = fmaf(hv3, dv.w, dot);
    }
}

// =====================================================================
// Fused producers + selector consumer. 256 WGs x 512 thr.
// WGs 0-127 (consumer): rec_sel v7 (r11-r15 verified), gi reads from
//   the depth-128-t ring, gated by jobs_done[chunk].
// WGs 128-255 (producers): gi_c ring chunks (coherent, backpressured on
//   consumer flags >= 64*(c-1) for c>=2 — ring slot c-2 then fully
//   consumed), interleaved with giFull = emb@Wih0^T+bih0 (bf16, normal
//   stores; visible to later kernels at kernel completion) and bf16
//   weight prep. Producers wait only on monotone consumer progress ->
//   deadlock-free; 256 WGs co-resident (1 WG/CU at 159KB LDS).
// =====================================================================
__global__ __launch_bounds__(512) void sel_fused(
    const float* __restrict__ emb, const float* __restrict__ Wih_c,
    const float* __restrict__ bih_c, float* __restrict__ ring,
    const float* __restrict__ Whh, const float* __restrict__ bhh,
    const float* __restrict__ Ws, const float* __restrict__ bs,
    float* __restrict__ h0, float* __restrict__ h1,
    unsigned long long* __restrict__ selm, int* __restrict__ flags,
    int* __restrict__ jobs,
    const float* __restrict__ Wih0, const float* __restrict__ bih0,
    unsigned short* __restrict__ giFull,
    const float* __restrict__ Whh0, const float* __restrict__ Whh1,
    const float* __restrict__ Wih1,
    const float* __restrict__ Wc3, const float* __restrict__ Wc4,
    const float* __restrict__ Wc5, unsigned short* __restrict__ wpack)
{
    __shared__ __align__(16) char smem[162816];   // consumer 159KB / producer 8.7KB
    const int tid = threadIdx.x;
    const int bx = blockIdx.x;

    if (bx >= 128) {
        // ------------------- PRODUCERS -------------------
        const int p = bx - 128;
        float* As = (float*)smem;
        float* Bs = As + 16 * 68;

        // gi ring chunks 0,1 (no backpressure needed)
        for (int c = 0; c < 2; ++c) {
            for (int j = p; j < 1536; j += 128) {
                const int b = j / 24, n = j % 24;
                prod_job<true>(b * 8 + c, n * 64, b * 128 + (c & 1) * 64,
                               emb, Wih_c, bih_c, ring, nullptr, As, Bs, tid);
                asm volatile("s_waitcnt vmcnt(0)" ::: "memory");
                __syncthreads();
                if (tid == 0)
                    __hip_atomic_fetch_add(jobs + c, 1, __ATOMIC_RELAXED,
                                           __HIP_MEMORY_SCOPE_AGENT);
                __syncthreads();
            }
        }
        // interleave: giFull group | backpressure | gi chunk c
        int fg = 0;
        for (int c = 2; c < 8; ++c) {
            if (fg < 8) {
                for (int j = p; j < 1536; j += 128) {
                    const int b = j / 24, n = j % 24;
                    prod_job<false>(b * 8 + fg, n * 64, 0,
                                    emb, Wih0, bih0, nullptr, giFull, As, Bs, tid);
                }
                ++fg;
            }
            poll128_ge(flags, 64 * (c - 1), tid);   // slot (c-2) fully consumed
            for (int j = p; j < 1536; j += 128) {
                const int b = j / 24, n = j % 24;
                prod_job<true>(b * 8 + c, n * 64, b * 128 + (c & 1) * 64,
                               emb, Wih_c, bih_c, ring, nullptr, As, Bs, tid);
                asm volatile("s_waitcnt vmcnt(0)" ::: "memory");
                __syncthreads();
                if (tid == 0)
                    __hip_atomic_fetch_add(jobs + c, 1, __ATOMIC_RELAXED,
                                           __HIP_MEMORY_SCOPE_AGENT);
                __syncthreads();
            }
        }
        while (fg < 8) {
            for (int j = p; j < 1536; j += 128) {
                const int b = j / 24, n = j % 24;
                prod_job<false>(b * 8 + fg, n * 64, 0,
                                emb, Wih0, bih0, nullptr, giFull, As, Bs, tid);
            }
            ++fg;
        }
        // bf16 weight prep (normal stores; consumed by later kernels)
        for (int i = p * 512 + tid; i < WP_N6; i += 128 * 512) {
            float v;
            if      (i < WP_N0) v = Whh0[i];
            else if (i < WP_N1) v = Whh1[i - WP_N0];
            else if (i < WP_N2) v = Wih0[i - WP_N1];
            else if (i < WP_N3) v = Wih1[i - WP_N2];
            else if (i < WP_N4) v = Wc3[i - WP_N3];
            else if (i < WP_N5) v = Wc4[i - WP_N4];
            else                v = Wc5[i - WP_N5];
            wpack[i] = f2bu(v);
        }
        return;
    }

    // ------------------- CONSUMER: rec_sel v7 (ring reads) -------------------
    float* Wl    = (float*)smem;           // 6144
    float* dWl   = Wl + 6144;              // 512
    float* hs    = dWl + 512;              // 32768
    float* partR = hs + 32768;             // 256
    float* partZ = partR + 256;            // 256
    float* partN = partZ + 256;            // 256
    float* pdot  = partN + 256;            // 512

    const int b = tid & 63;
    const int w = __builtin_amdgcn_readfirstlane(tid >> 6);
    const int u = w >> 1, s = w & 1;
    const int iu = bx * 4 + u;

    for (int idx = tid; idx < 12 * 512; idx += 512) {
        int rr = idx >> 9, k = idx & 511;
        int ul = rr / 3, gate = rr - ul * 3;
        Wl[idx] = Whh[((size_t)gate * 512 + bx * 4 + ul) * 512 + k];
    }
    dWl[tid] = Ws[512 + tid] - Ws[tid];
    __syncthreads();

    const float bR = bhh[iu], bZ = bhh[512 + iu], bN = bhh[1024 + iu];
    const float db = bs[1] - bs[0];
    const float* __restrict__ wR = Wl + (u*3 + 0) * 512;
    const float* __restrict__ wZ = Wl + (u*3 + 1) * 512;
    const float* __restrict__ wN = Wl + (u*3 + 2) * 512;

    // gi(t=0) prefetch — gated on chunk 0, coherent, ring slot 0
    float pgR = 0.f, pgZ = 0.f, pgN = 0.f;
    int ready_chunk = 0;
    if (s == 0) {
        poll_cnt(jobs + 0, 1536);
        ready_chunk = 1;
        const float* gp = ring + (size_t)(b * 128) * G_;
        asm volatile("global_load_dword %0, %3, off sc0 sc1\n\t"
                     "global_load_dword %1, %4, off sc0 sc1\n\t"
                     "global_load_dword %2, %5, off sc0 sc1\n\t"
                     "s_waitcnt vmcnt(0)"
                     : "=&v"(pgR), "=&v"(pgZ), "=&v"(pgN)
                     : "v"(gp + iu), "v"(gp + 512 + iu), "v"(gp + 1024 + iu)
                     : "memory");
    }

    for (int t = 0; t <= T_; ++t) {
        const bool comp = (t < T_);
        const float* hcur = (t & 1) ? h1 : h0;
        float* hnxt = (t & 1) ? h0 : h1;

        if (t > 0) bar_wait128(flags, t, tid);

        // ---- single-shot stage of full h(t): 16 CLOAD4/thread ----
        const float* hc = hcur + (size_t)tid * 4;
        float* hd = hs + tid * 4;
        float4 a0,a1,a2,a3,a4,a5,a6,a7,a8,a9,aa,ab,ac,ad,ae,af;
        CLOAD4(a0, hc +  0*2048); CLOAD4(a1, hc +  1*2048);
        CLOAD4(a2, hc +  2*2048); CLOAD4(a3, hc +  3*2048);
        CLOAD4(a4, hc +  4*2048); CLOAD4(a5, hc +  5*2048);
        CLOAD4(a6, hc +  6*2048); CLOAD4(a7, hc +  7*2048);
        CLOAD4(a8, hc +  8*2048); CLOAD4(a9, hc +  9*2048);
        CLOAD4(aa, hc + 10*2048); CLOAD4(ab, hc + 11*2048);
        CLOAD4(ac, hc + 12*2048); CLOAD4(ad, hc + 13*2048);
        CLOAD4(ae, hc + 14*2048); CLOAD4(af, hc + 15*2048);
        CWAIT();
        *(float4*)(hd +  0*2048) = a0; *(float4*)(hd +  1*2048) = a1;
        *(float4*)(hd +  2*2048) = a2; *(float4*)(hd +  3*2048) = a3;
        *(float4*)(hd +  4*2048) = a4; *(float4*)(hd +  5*2048) = a5;
        *(float4*)(hd +  6*2048) = a6; *(float4*)(hd +  7*2048) = a7;
        *(float4*)(hd +  8*2048) = a8; *(float4*)(hd +  9*2048) = a9;
        *(float4*)(hd + 10*2048) = aa; *(float4*)(hd + 11*2048) = ab;
        *(float4*)(hd + 12*2048) = ac; *(float4*)(hd + 13*2048) = ad;
        *(float4*)(hd + 14*2048) = ae; *(float4*)(hd + 15*2048) = af;
        __syncthreads();

        float aR = (s == 0) ? bR : 0.f;
        float aZ = (s == 0) ? bZ : 0.f;
        float aN = (s == 0) ? bN : 0.f;
        float dot = 0.f, hp = 0.f;

        if (comp) {
            gates_abs(hs, b, s * 128,       wR, wZ, wN, aR, aZ, aN);
            gates_abs(hs, b, 256 + s * 128, wR, wZ, wN, aR, aZ, aN);
            if (s == 0) hp = hs[iu * 64 + b];
        }
        dot_abs(hs, b, (w < 4) ? w * 64 : 256 + (w - 4) * 64, dWl, dot);

        if (comp && s == 1) {
            partR[u*64 + b] = aR; partZ[u*64 + b] = aZ; partN[u*64 + b] = aN;
        }
        pdot[w*64 + b] = dot;
        __syncthreads();

        if (comp && s == 0) {
            aR += partR[u*64 + b]; aZ += partZ[u*64 + b]; aN += partN[u*64 + b];
            const float r = sigm(pgR + aR);
            const float z = sigm(pgZ + aZ);
            const float n = tanhf(pgN + r * aN);
            const float hn = (1.f - z) * n + z * hp;
            const float* hdst = hnxt + (size_t)iu * 64 + b;
            CSTORE4(hdst, hn);
        }

        if (t < T_) {
            bar_arrive(flags, t, tid, bx);
            // gi(t+1) prefetch after flag store; ring slot (t+1)&127
            if (s == 0 && t + 1 < T_) {
                const int nc = (t + 1) >> 6;
                if (nc >= ready_chunk) { poll_cnt(jobs + nc, 1536); ready_chunk = nc + 1; }
                const float* gp = ring + (size_t)(b * 128 + ((t + 1) & 127)) * G_;
                asm volatile("global_load_dword %0, %3, off sc0 sc1\n\t"
                             "global_load_dword %1, %4, off sc0 sc1\n\t"
                             "global_load_dword %2, %5, off sc0 sc1\n\t"
                             "s_waitcnt vmcnt(0)"
                             : "=&v"(pgR), "=&v"(pgZ), "=&v"(pgN)
                             : "v"(gp + iu), "v"(gp + 512 + iu), "v"(gp + 1024 + iu)
                             : "memory");
            }
        }
        if (w == 0 && t >= 1) {
            float p2 = pdot[0*64 + b];
            p2 += pdot[1*64 + b]; p2 += pdot[2*64 + b]; p2 += pdot[3*64 + b];
            p2 += pdot[4*64 + b]; p2 += pdot[5*64 + b]; p2 += pdot[6*64 + b];
            p2 += pdot[7*64 + b];
            unsigned long long m = __ballot((p2 + db) > 0.f);
            if (tid == 0 && bx == 0) selm[t - 1] = m;
        }
    }
}

// =====================================================================
// FUSED layer0 -> gi1 -> layer1 pipeline (r13/r15 verified structure;
// r16: layer0 reads giFull[b][order[b][t]] — gather via index, gi0
// GEMM eliminated).
// =====================================================================
template<int ROLE>
__device__ __forceinline__ void layer_body(
    int wg, int tid,
    const unsigned short* __restrict__ gi0,     // ROLE0: giFull (all rows)
    const int* __restrict__ order,              // ROLE0 only
    const unsigned short* __restrict__ ring1,   // ROLE1: gi1 ring
    unsigned short* __restrict__ ring0,
    const unsigned short* __restrict__ wbf, const float* __restrict__ bhh,
    const int* __restrict__ nselp, const int* __restrict__ maxnp,
    unsigned short* __restrict__ hA, unsigned short* __restrict__ hB,
    float* __restrict__ outp,
    int* __restrict__ flagsSelf, const int* __restrict__ flagsB,
    unsigned char* ldsW, unsigned char* ldsH, float* gbuf)
{
    const int l = tid & 63;
    const int q = tid >> 6;
    const int i0 = wg * 16;
    const int b = tid & 63;

    for (int idx = tid; idx < 48 * 64; idx += 256) {
        const int r = idx >> 6, seg = idx & 63;
        const int tier = r >> 4, ul = r & 15;
        const float4 v = *(const float4*)((const char*)wbf
            + ((size_t)(tier * 512 + i0 + ul) * 512) * 2 + seg * 16);
        *(float4*)(ldsW + r * 1040 + seg * 16) = v;
    }
    const float4 bRv = *(const float4*)(bhh + i0 + 4 * q);
    const float4 bZv = *(const float4*)(bhh + 512 + i0 + 4 * q);
    const float4 bNv = *(const float4*)(bhh + 1024 + i0 + 4 * q);
    const int ns = nselp[b];
    const int TOTAL = *maxnp;

    uint2 gR, gZ, gN;
    if (ROLE == 0) {
        const int oi = order[b * T_];
        const unsigned short* gp = gi0 + ((size_t)b * T_ + oi) * (size_t)G_ + i0 + 4 * q;
        gR = *(const uint2*)gp;
        gZ = *(const uint2*)(gp + 512);
        gN = *(const uint2*)(gp + 1024);
    }
    __syncthreads();

    for (int t = 0; t < TOTAL; ++t) {
        const unsigned short* hcur = (t & 1) ? hB : hA;
        unsigned short* hnxt = (t & 1) ? hA : hB;

        if (t > 0) bar_wait<32>(flagsSelf, t, tid);
        if (ROLE == 0) {
            if (t >= 4) poll_ge<24>(flagsB, t - 3, tid);
        } else {
            poll_ge<24>(flagsB, t + 1, tid);
            const unsigned short* gp = ring1 + ((size_t)(t & 3) * 64 + b) * G_ + i0 + 4 * q;
            CLOAD2(gR, gp); CLOAD2(gZ, gp + 512); CLOAD2(gN, gp + 1024);
        }

        {
            const char* src = (const char*)hcur + tid * 256;
            float4 s0, s1, s2, s3, s4, s5, s6, s7, s8, s9, sa, sb_, sc, sd, se, sf;
            CLOAD4(s0, src + 0 * 16);  CLOAD4(s1, src + 1 * 16);
            CLOAD4(s2, src + 2 * 16);  CLOAD4(s3, src + 3 * 16);
            CLOAD4(s4, src + 4 * 16);  CLOAD4(s5, src + 5 * 16);
            CLOAD4(s6, src + 6 * 16);  CLOAD4(s7, src + 7 * 16);
            CLOAD4(s8, src + 8 * 16);  CLOAD4(s9, src + 9 * 16);
            CLOAD4(sa, src + 10 * 16); CLOAD4(sb_, src + 11 * 16);
            CLOAD4(sc, src + 12 * 16); CLOAD4(sd, src + 13 * 16);
            CLOAD4(se, src + 14 * 16); CLOAD4(sf, src + 15 * 16);
            CWAIT();
            char* dst = (char*)ldsH + (tid >> 2) * 1040 + (tid & 3) * 256;
            *(float4*)(dst + 0 * 16) = s0;  *(float4*)(dst + 1 * 16) = s1;
            *(float4*)(dst + 2 * 16) = s2;  *(float4*)(dst + 3 * 16) = s3;
            *(float4*)(dst + 4 * 16) = s4;  *(float4*)(dst + 5 * 16) = s5;
            *(float4*)(dst + 6 * 16) = s6;  *(float4*)(dst + 7 * 16) = s7;
            *(float4*)(dst + 8 * 16) = s8;  *(float4*)(dst + 9 * 16) = s9;
            *(float4*)(dst + 10 * 16) = sa; *(float4*)(dst + 11 * 16) = sb_;
            *(float4*)(dst + 12 * 16) = sc; *(float4*)(dst + 13 * 16) = sd;
            *(float4*)(dst + 14 * 16) = se; *(float4*)(dst + 15 * 16) = sf;
        }
        __syncthreads();

        f32x4 ac0 = {0.f, 0.f, 0.f, 0.f};
        f32x4 ac1 = {0.f, 0.f, 0.f, 0.f};
        f32x4 ac2 = {0.f, 0.f, 0.f, 0.f};
        {
            const char* ab2 = (const char*)ldsH + (q * 16 + (l & 15)) * 1040 + (l >> 4) * 16;
            const char* bb = (const char*)ldsW + (l & 15) * 1040 + (l >> 4) * 16;
            #pragma unroll
            for (int ks = 0; ks < 16; ++ks) {
                const bf16x8 av = *(const bf16x8*)(ab2 + ks * 64);
                const bf16x8 w0 = *(const bf16x8*)(bb + ks * 64);
                const bf16x8 w1 = *(const bf16x8*)(bb + 16 * 1040 + ks * 64);
                const bf16x8 w2 = *(const bf16x8*)(bb + 32 * 1040 + ks * 64);
                ac0 = __builtin_amdgcn_mfma_f32_16x16x32_bf16(av, w0, ac0, 0, 0, 0);
                ac1 = __builtin_amdgcn_mfma_f32_16x16x32_bf16(av, w1, ac1, 0, 0, 0);
                ac2 = __builtin_amdgcn_mfma_f32_16x16x32_bf16(av, w2, ac2, 0, 0, 0);
            }
        }
        {
            const int gcol = q * 16 + 4 * (l >> 4);
            const int grow = l & 15;
            #pragma unroll
            for (int r = 0; r < 4; ++r) {
                gbuf[grow * 66 + gcol + r]        = ac0[r];
                gbuf[(16 + grow) * 66 + gcol + r] = ac1[r];
                gbuf[(32 + grow) * 66 + gcol + r] = ac2[r];
            }
        }
        __syncthreads();

        {
            const ushort4 hp4 = *(const ushort4*)((const char*)ldsH
                                 + b * 1040 + (i0 + 4 * q) * 2);
            const unsigned short hpb[4] = {hp4.x, hp4.y, hp4.z, hp4.w};
            const float irv[4] = {b2f(gR.x & 0xffff), b2f(gR.x >> 16),
                                  b2f(gR.y & 0xffff), b2f(gR.y >> 16)};
            const float izv[4] = {b2f(gZ.x & 0xffff), b2f(gZ.x >> 16),
                                  b2f(gZ.y & 0xffff), b2f(gZ.y >> 16)};
            const float inv[4] = {b2f(gN.x & 0xffff), b2f(gN.x >> 16),
                                  b2f(gN.y & 0xffff), b2f(gN.y >> 16)};
            float4 o;
            unsigned short ob[4];
            #pragma unroll
            for (int j = 0; j < 4; ++j) {
                const int u2 = 4 * q + j;
                const float hr = gbuf[u2 * 66 + b]        + bRv[j];
                const float hz = gbuf[(16 + u2) * 66 + b] + bZv[j];
                const float hn = gbuf[(32 + u2) * 66 + b] + bNv[j];
                const float rr = sigm(irv[j] + hr);
                const float zz = sigm(izv[j] + hz);
                const float nn = tanhf(inv[j] + rr * hn);
                const float hpf = b2f(hpb[j]);
                float hv = (1.f - zz) * nn + zz * hpf;
                if (t >= ns) hv = hpf;
                ((float*)&o)[j] = hv;
                ob[j] = f2bu(hv);
            }
            uint2 hpk;
            hpk.x = (unsigned)ob[0] | ((unsigned)ob[1] << 16);
            hpk.y = (unsigned)ob[2] | ((unsigned)ob[3] << 16);
            if (ROLE == 0) {
                const unsigned short* rdst = ring0 + ((size_t)(t & 3) * 64 + b) * 512 + i0 + 4 * q;
                CSTORE8(rdst, hpk);
            } else {
                if (t < ns)
                    *(float4*)(outp + ((size_t)b * T_ + t) * 512 + i0 + 4 * q) = o;
            }
            const unsigned short* hdst = hnxt + (size_t)b * 512 + i0 + 4 * q;
            CSTORE8(hdst, hpk);
        }

        bar_arrive(flagsSelf, t, tid, wg);
        if (ROLE == 0 && t + 1 < TOTAL) {
            const int oi = order[b * T_ + (t + 1)];
            const unsigned short* gp = gi0 + ((size_t)b * T_ + oi) * (size_t)G_ + i0 + 4 * q;
            gR = *(const uint2*)gp;
            gZ = *(const uint2*)(gp + 512);
            gN = *(const uint2*)(gp + 1024);
        }
    }
}

__global__ __launch_bounds__(256) void rec_fused(
    const unsigned short* __restrict__ giFull, const int* __restrict__ order,
    const unsigned short* __restrict__ wbf0,
    const unsigned short* __restrict__ wbf1,
    const unsigned short* __restrict__ wih1b,
    const float* __restrict__ bhh0, const float* __restrict__ bhh1,
    const float* __restrict__ bih1,
    const int* __restrict__ nselp, const int* __restrict__ maxnp,
    unsigned short* __restrict__ h0A, unsigned short* __restrict__ h1A,
    unsigned short* __restrict__ h0C, unsigned short* __restrict__ h1C,
    unsigned short* __restrict__ ring0, unsigned short* __restrict__ ring1,
    float* __restrict__ outp,
    int* __restrict__ flagsA, int* __restrict__ flagsB, int* __restrict__ flagsC)
{
    __shared__ __align__(16) unsigned char ldsX[64 * 1040];
    __shared__ __align__(16) unsigned char ldsY[64 * 1040];
    __shared__ float gbuf[48 * 66];

    const int tid = threadIdx.x;
    const int bx = blockIdx.x;

    if (bx < 32) {
        layer_body<0>(bx, tid, giFull, order, nullptr, ring0, wbf0, bhh0, nselp, maxnp,
                      h0A, h1A, nullptr, flagsA, flagsB, ldsX, ldsY, gbuf);
    } else if (bx < 56) {
        const int wg = bx - 32;
        const int l = tid & 63;
        const int q = tid >> 6;
        const int n0 = wg * 64;

        for (int idx = tid; idx < 64 * 64; idx += 256) {
            const int r = idx >> 6, seg = idx & 63;
            const float4 v = *(const float4*)((const char*)wih1b
                + ((size_t)(n0 + r) * 512) * 2 + seg * 16);
            *(float4*)(ldsX + r * 1040 + seg * 16) = v;
        }
        float bv[4];
        #pragma unroll
        for (int s = 0; s < 4; ++s) bv[s] = bih1[n0 + s * 16 + (l & 15)];
        const int TOTAL = *maxnp;
        __syncthreads();

        for (int t = 0; t < TOTAL; ++t) {
            poll_ge<32>(flagsA, t + 1, tid);
            if (t >= 4) poll_ge<32>(flagsC, t - 3, tid);

            {
                const char* src = (const char*)ring0 + (size_t)(t & 3) * 65536 + tid * 256;
                float4 s0, s1, s2, s3, s4, s5, s6, s7, s8, s9, sa, sb_, sc, sd, se, sf;
                CLOAD4(s0, src + 0 * 16);  CLOAD4(s1, src + 1 * 16);
                CLOAD4(s2, src + 2 * 16);  CLOAD4(s3, src + 3 * 16);
                CLOAD4(s4, src + 4 * 16);  CLOAD4(s5, src + 5 * 16);
                CLOAD4(s6, src + 6 * 16);  CLOAD4(s7, src + 7 * 16);
                CLOAD4(s8, src + 8 * 16);  CLOAD4(s9, src + 9 * 16);
                CLOAD4(sa, src + 10 * 16); CLOAD4(sb_, src + 11 * 16);
                CLOAD4(sc, src + 12 * 16); CLOAD4(sd, src + 13 * 16);
                CLOAD4(se, src + 14 * 16); CLOAD4(sf, src + 15 * 16);
                CWAIT();
                char* dst = (char*)ldsY + (tid >> 2) * 1040 + (tid & 3) * 256;
                *(float4*)(dst + 0 * 16) = s0;  *(float4*)(dst + 1 * 16) = s1;
                *(float4*)(dst + 2 * 16) = s2;  *(float4*)(dst + 3 * 16) = s3;
                *(float4*)(dst + 4 * 16) = s4;  *(float4*)(dst + 5 * 16) = s5;
                *(float4*)(dst + 6 * 16) = s6;  *(float4*)(dst + 7 * 16) = s7;
                *(float4*)(dst + 8 * 16) = s8;  *(float4*)(dst + 9 * 16) = s9;
                *(float4*)(dst + 10 * 16) = sa; *(float4*)(dst + 11 * 16) = sb_;
                *(float4*)(dst + 12 * 16) = sc; *(float4*)(dst + 13 * 16) = sd;
                *(float4*)(dst + 14 * 16) = se; *(float4*)(dst + 15 * 16) = sf;
            }
            __syncthreads();

            f32x4 acc0 = {0.f,0.f,0.f,0.f}, acc1 = {0.f,0.f,0.f,0.f};
            f32x4 acc2 = {0.f,0.f,0.f,0.f}, acc3 = {0.f,0.f,0.f,0.f};
            {
                const char* ab2 = (const char*)ldsY + (q * 16 + (l & 15)) * 1040 + (l >> 4) * 16;
                const char* bb = (const char*)ldsX + (l & 15) * 1040 + (l >> 4) * 16;
                #pragma unroll
                for (int ks = 0; ks < 16; ++ks) {
                    const bf16x8 av = *(const bf16x8*)(ab2 + ks * 64);
                    const bf16x8 b0 = *(const bf16x8*)(bb + ks * 64);
                    const bf16x8 b1 = *(const bf16x8*)(bb + 16 * 1040 + ks * 64);
                    const bf16x8 b2 = *(const bf16x8*)(bb + 32 * 1040 + ks * 64);
                    const bf16x8 b3 = *(const bf16x8*)(bb + 48 * 1040 + ks * 64);
                    acc0 = __builtin_amdgcn_mfma_f32_16x16x32_bf16(av, b0, acc0, 0, 0, 0);
                    acc1 = __builtin_amdgcn_mfma_f32_16x16x32_bf16(av, b1, acc1, 0, 0, 0);
                    acc2 = __builtin_amdgcn_mfma_f32_16x16x32_bf16(av, b2, acc2, 0, 0, 0);
                    acc3 = __builtin_amdgcn_mfma_f32_16x16x32_bf16(av, b3, acc3, 0, 0, 0);
                }
            }
            f32x4 accs[4] = {acc0, acc1, acc2, acc3};
            #pragma unroll
            for (int s = 0; s < 4; ++s) {
                const int col = n0 + s * 16 + (l & 15);
                #pragma unroll
                for (int reg = 0; reg < 4; ++reg) {
                    const int m = q * 16 + (l >> 4) * 4 + reg;
                    const unsigned val = f2bu(accs[s][reg] + bv[s]);
                    const unsigned short* dst = ring1 + ((size_t)(t & 3) * 64 + m) * G_ + col;
                    CSTORE2(dst, val);
                }
            }
            bar_arrive(flagsB, t, tid, wg);
        }
    } else {
        layer_body<1>(bx - 56, tid, nullptr, nullptr, ring1, nullptr, wbf1, bhh1, nselp, maxnp,
                      h0C, h1C, outp, flagsC, flagsB, ldsX, ldsY, gbuf);
    }
}

// =====================================================================
// Per-batch selection post-processing (unchanged, selm version).
// =====================================================================
__global__ void build_order_k(const int* __restrict__ mask,
                              const unsigned long long* __restrict__ selm,
                              int* __restrict__ order, int* __restrict__ nsel,
                              int* __restrict__ maxn)
{
    const int b = threadIdx.x;
    int lens = 0;
    for (int t = 0; t < T_; ++t) lens += (mask[b * T_ + t] != 0);
    int cnt = 0;
    for (int t = 0; t < T_; ++t) {
        int s = (int)((selm[t] >> b) & 1ull);
        if (t == 0) s = 1;
        if (t == lens - 1) s = 1;
        if (t >= lens) s = 0;
        if (s) order[b * T_ + (cnt++)] = t;
    }
    nsel[b] = cnt;
    int c2 = cnt;
    for (int t = 0; t < T_; ++t) {
        int s = (int)((selm[t] >> b) & 1ull);
        if (t == 0) s = 1;
        if (t == lens - 1) s = 1;
        if (t >= lens) s = 0;
        if (!s) order[b * T_ + (c2++)] = t;
    }
    __shared__ int red[64];
    red[b] = cnt;
    __syncthreads();
    if (b == 0) {
        int m = 0;
        for (int qq = 0; qq < 64; ++qq) m = max(m, red[qq]);
        *maxn = m;
    }
}

// =====================================================================
// Final linear (unchanged).
// =====================================================================
__global__ void final_k(const unsigned int* __restrict__ pool,
                        const float* __restrict__ Wo, const float* __restrict__ bo,
                        float* __restrict__ out)
{
    const int b = threadIdx.x;
    float s = bo[0];
    for (int f = 0; f < 3 * NF_; ++f)
        s = fmaf(__uint_as_float(pool[b * (3*NF_) + f]), Wo[f], s);
    out[b] = s;
}

// =====================================================================
extern "C" void kernel_launch(void* const* d_in, const int* in_sizes, int n_in,
                              void* d_out, int out_size, void* d_ws, size_t ws_size,
                              hipStream_t stream)
{
    (void)in_sizes; (void)n_in; (void)out_size;
    const float* emb   = (const float*)d_in[0];
    const int*   mask  = (const int*)d_in[1];
    const float* Wih_c = (const float*)d_in[2];
    const float* Whh_c = (const float*)d_in[3];
    const float* bih_c = (const float*)d_in[4];
    const float* bhh_c = (const float*)d_in[5];
    const float* Ws    = (const float*)d_in[6];
    const float* bs    = (const float*)d_in[7];
    const float* Wih0  = (const float*)d_in[8];
    const float* Whh0  = (const float*)d_in[9];
    const float* bih0  = (const float*)d_in[10];
    const float* bhh0  = (const float*)d_in[11];
    const float* Wih1  = (const float*)d_in[12];
    const float* Whh1  = (const float*)d_in[13];
    const float* bih1  = (const float*)d_in[14];
    const float* bhh1  = (const float*)d_in[15];
    const float* Wc3   = (const float*)d_in[16];
    const float* bc3   = (const float*)d_in[17];
    const float* Wc4   = (const float*)d_in[18];
    const float* bc4   = (const float*)d_in[19];
    const float* Wc5   = (const float*)d_in[20];
    const float* bc5   = (const float*)d_in[21];
    const float* Wo    = (const float*)d_in[22];
    const float* bo    = (const float*)d_in[23];

    if (ws_size < WS_NEED) return;
    char* ws = (char*)d_ws;
    float*          ring   = (float*)(ws + OFF_RING_GI);
    float*          outbuf = (float*)(ws + OFF_OUT);
    unsigned short* giFull = (unsigned short*)(ws + OFF_GIFULL);
    unsigned short* wpack  = (unsigned short*)(ws + OFF_WBF0);
    unsigned short* wbf0   = (unsigned short*)(ws + OFF_WBF0);
    unsigned short* wbf1   = (unsigned short*)(ws + OFF_WBF1);
    unsigned short* wih1b  = (unsigned short*)(ws + OFF_WIH1);
    unsigned short* wc3b   = (unsigned short*)(ws + OFF_WC3);
    unsigned short* wc4b   = (unsigned short*)(ws + OFF_WC4);
    unsigned short* wc5b   = (unsigned short*)(ws + OFF_WC5);
    float*          h0f    = (float*)(ws + OFF_H0);
    float*          h1f    = (float*)(ws + OFF_H1);
    unsigned short* h0A    = (unsigned short*)(ws + OFF_H0);
    unsigned short* h1A    = (unsigned short*)(ws + OFF_H0 + 65536);
    unsigned short* h0C    = (unsigned short*)(ws + OFF_H0 + 131072);
    unsigned short* h1C    = (unsigned short*)(ws + OFF_H0 + 196608);
    unsigned long long* selm = (unsigned long long*)(ws + OFF_SEL);
    int*            order  = (int*)(ws + OFF_ORD);
    int*            nsel   = (int*)(ws + OFF_NSEL);
    int*            maxn   = (int*)(ws + OFF_MAXN);
    int*            flagsA = (int*)(ws + OFF_FLG);
    int*            flagsB = (int*)(ws + OFF_FLG + 128);
    int*            flagsC = (int*)(ws + OFF_FLG + 256);
    int*            jobs   = (int*)(ws + OFF_JOBS);
    unsigned int*   pool   = (unsigned int*)(ws + OFF_POOL);
    unsigned short* ring0  = (unsigned short*)(ws + OFF_RING0);
    unsigned short* ring1  = (unsigned short*)(ws + OFF_RING1);

    // 1+2. fused producers (gi ring + giFull + weight prep) + selector
    hipMemsetAsync(flagsA, 0, 1024, stream);   // sel flags + jobs counters
    hipMemsetAsync(h0f, 0, (size_t)B_ * H_ * 4, stream);
    sel_fused<<<256, 512, 0, stream>>>(emb, Wih_c, bih_c, ring, Whh_c, bhh_c,
                                       Ws, bs, h0f, h1f, selm, flagsA, jobs,
                                       Wih0, bih0, giFull,
                                       Whh0, Whh1, Wih1, Wc3, Wc4, Wc5, wpack);
    // 3. forcing + stable partition
    build_order_k<<<1, 64, 0, stream>>>(mask, selm, order, nsel, maxn);
    // 4. FUSED layer0 -> gi1 -> layer1 pipeline (layer0 gathers giFull)
    hipMemsetAsync(flagsA, 0, 512, stream);
    hipMemsetAsync(h0A, 0, 65536, stream);
    hipMemsetAsync(h0C, 0, 65536, stream);
    hipMemsetAsync(outbuf, 0, (size_t)B_ * T_ * H_ * 4, stream);   // ring dead now
    rec_fused<<<88, 256, 0, stream>>>(giFull, order, wbf0, wbf1, wih1b,
                                      bhh0, bhh1, bih1,
                                      nsel, maxn, h0A, h1A, h0C, h1C,
                                      ring0, ring1, outbuf, flagsA, flagsB, flagsC);
    // 5. convs (bf16 MFMA sliding-window, supertile) + relu + time-max pooling
    hipMemsetAsync(pool, 0, (size_t)B_ * 3 * NF_ * 4, stream);
    gemm_mfma<2,1><<<dim3(512 * 4), 256, 0, stream>>>(outbuf, wc3b, bc3, nullptr, pool,
                                                      NF_, 3*H_, H_, 510, 8, 4, nullptr, nullptr, 0);
    gemm_mfma<2,1><<<dim3(512 * 4), 256, 0, stream>>>(outbuf, wc4b, bc4, nullptr, pool,
                                                      NF_, 4*H_, H_, 509, 8, 4, nullptr, nullptr, 256);
    gemm_mfma<2,1><<<dim3(512 * 4), 256, 0, stream>>>(outbuf, wc5b, bc5, nullptr, pool,
                                                      NF_, 5*H_, H_, 508, 8, 4, nullptr, nullptr, 512);
    // 6. final linear -> d_out (64 f32)
    final_k<<<1, 64, 0, stream>>>(pool, Wo, bo, (float*)d_out);
}

// Round 17
// 9670.338 us; speedup vs baseline: 1.1854x; 1.1854x over previous
//
#include <hip/hip_runtime.h>
#include <hip/hip_bf16.h>
#include <cstddef>

// ---------------- problem constants ----------------
constexpr int B_ = 64, T_ = 512, E_ = 768, H_ = 512, G_ = 1536, NF_ = 256;

typedef float f32x4 __attribute__((ext_vector_type(4)));
typedef __bf16 bf16x8 __attribute__((ext_vector_type(8)));

// ---------------- workspace layout (bytes) ----------------
constexpr size_t SZ_GIC   = (size_t)B_ * T_ * G_ * 4;       // 192 MiB
constexpr size_t OFF_GI   = 0;                              // f32 gi_c / later bf16 gi
constexpr size_t OFF_OUT  = (size_t)B_ * T_ * G_ * 2;       // 96MiB: out1 f32 (64MiB)
// bf16 weight copies alias gi_c's tail -> wprep must run AFTER sel_fused.
constexpr size_t OFF_WBF0 = 170u * 1024 * 1024;
constexpr size_t OFF_WBF1 = OFF_WBF0 + (size_t)G_ * H_ * 2;
constexpr size_t OFF_WIH0 = OFF_WBF1 + (size_t)G_ * H_ * 2;
constexpr size_t OFF_WIH1 = OFF_WIH0 + (size_t)G_ * E_ * 2;
constexpr size_t OFF_WC3  = OFF_WIH1 + (size_t)G_ * H_ * 2;
constexpr size_t OFF_WC4  = OFF_WC3 + (size_t)NF_ * 3 * H_ * 2;
constexpr size_t OFF_WC5  = OFF_WC4 + (size_t)NF_ * 4 * H_ * 2;
constexpr size_t OFF_MISC = SZ_GIC;
constexpr size_t OFF_H0   = OFF_MISC;                       // 256KB
constexpr size_t OFF_H1   = OFF_H0 + (size_t)B_ * H_ * 4;
constexpr size_t OFF_SEL  = OFF_H1 + (size_t)B_ * H_ * 4;   // uint64 selm[T_]
constexpr size_t OFF_ORD  = OFF_SEL + (size_t)B_ * T_ * 4;
constexpr size_t OFF_NSEL = OFF_ORD + (size_t)B_ * T_ * 4;
constexpr size_t OFF_MAXN = OFF_NSEL + 256;
constexpr size_t OFF_FLG  = OFF_MAXN + 256;   // sel flags[128] / fused A,B,C
constexpr size_t OFF_JOBS = OFF_FLG + 512;    // jobs_done[8]
constexpr size_t OFF_POOL = OFF_FLG + 1024;
constexpr size_t OFF_RING0 = OFF_POOL + (size_t)B_ * 3 * NF_ * 4;   // out0 ring [4][64][512] bf16
constexpr size_t OFF_RING1 = OFF_RING0 + 4ull * 64 * 512 * 2;       // gi1 ring [4][64][1536] bf16
constexpr size_t WS_NEED  = OFF_RING1 + 4ull * 64 * 1536 * 2;

// merged weight-prep region sizes (elements)
constexpr int WP_N0 = G_ * H_;
constexpr int WP_N1 = WP_N0 + G_ * H_;
constexpr int WP_N2 = WP_N1 + G_ * E_;
constexpr int WP_N3 = WP_N2 + G_ * H_;
constexpr int WP_N4 = WP_N3 + NF_ * 3 * H_;
constexpr int WP_N5 = WP_N4 + NF_ * 4 * H_;
constexpr int WP_N6 = WP_N5 + NF_ * 5 * H_;

// coherent (fabric-level, L1/L2-bypass) access helpers
#define CLOAD4(dst, ptr) \
    asm volatile("global_load_dwordx4 %0, %1, off sc0 sc1" : "=v"(dst) : "v"(ptr))
#define CLOAD2(dst, ptr) \
    asm volatile("global_load_dwordx2 %0, %1, off sc0 sc1" : "=v"(dst) : "v"(ptr))
#define CWAIT() do { \
    asm volatile("s_waitcnt vmcnt(0)" ::: "memory"); \
    __builtin_amdgcn_sched_barrier(0); } while (0)
#define CSTORE4(ptr, val) \
    asm volatile("global_store_dword %0, %1, off sc0 sc1" :: "v"(ptr), "v"(val) : "memory")
#define CSTORE8(ptr, val) \
    asm volatile("global_store_dwordx2 %0, %1, off sc0 sc1" :: "v"(ptr), "v"(val) : "memory")
#define CSTORE2(ptr, val) \
    asm volatile("global_store_short %0, %1, off sc0 sc1" :: "v"(ptr), "v"(val) : "memory")
// 128-bit asm store input must be an ext_vector_type (f32x4), not the
// struct-based float4 (LLVM: "indirect register inputs" error).
#define CSTOREX4(ptr, val) \
    asm volatile("global_store_dwordx4 %0, %1, off sc0 sc1" :: "v"(ptr), "v"(val) : "memory")

__device__ __forceinline__ float sigm(float x) { return 1.f / (1.f + expf(-x)); }
__device__ __forceinline__ float b2f(unsigned short u) {
    return __uint_as_float(((unsigned int)u) << 16);
}
__device__ __forceinline__ unsigned short f2bu(float x) {
    __hip_bfloat16 h = __float2bfloat16(x);
    return *(unsigned short*)&h;
}

template<int NWG>
__device__ __forceinline__ void bar_wait(const int* flags, int t, int tid) {
    if (tid < 64) {
        int v;
        for (;;) {
            asm volatile("global_load_dword %0, %1, off sc0 sc1\n\t"
                         "s_waitcnt vmcnt(0)"
                         : "=v"(v) : "v"(flags + (tid & (NWG - 1))) : "memory");
            if (__all(v >= t)) break;
            __builtin_amdgcn_s_sleep(1);
        }
    }
    __syncthreads();
}

// poll first N flags until all >= thresh
template<int N>
__device__ __forceinline__ void poll_ge(const int* flags, int thresh, int tid) {
    if (tid < 64) {
        const int idx = (tid < N) ? tid : 0;
        int v;
        for (;;) {
            asm volatile("global_load_dword %0, %1, off sc0 sc1\n\t"
                         "s_waitcnt vmcnt(0)"
                         : "=v"(v) : "v"(flags + idx) : "memory");
            if (__all(v >= thresh)) break;
            __builtin_amdgcn_s_sleep(1);
        }
    }
    __syncthreads();
}

// per-wave spin on a single counter (all lanes same address)
__device__ __forceinline__ void poll_cnt(const int* p, int thr) {
    int v;
    for (;;) {
        asm volatile("global_load_dword %0, %1, off sc0 sc1\n\t"
                     "s_waitcnt vmcnt(0)"
                     : "=v"(v) : "v"(p) : "memory");
        if (__all(v >= thr)) break;
        __builtin_amdgcn_s_sleep(1);
    }
}

// 128-WG variant for rec_sel
__device__ __forceinline__ void bar_wait128(const int* flags, int t, int tid) {
    if (tid < 64) {
        int v1, v2;
        for (;;) {
            asm volatile("global_load_dword %0, %2, off sc0 sc1\n\t"
                         "global_load_dword %1, %3, off sc0 sc1\n\t"
                         "s_waitcnt vmcnt(0)"
                         : "=&v"(v1), "=&v"(v2)
                         : "v"(flags + tid), "v"(flags + tid + 64) : "memory");
            if (__all((v1 >= t) && (v2 >= t))) break;
            __builtin_amdgcn_s_sleep(1);
        }
    }
    __syncthreads();
}

__device__ __forceinline__ void bar_arrive(int* flags, int t, int tid, int idx) {
    asm volatile("s_waitcnt vmcnt(0)" ::: "memory");
    __syncthreads();
    if (tid == 0) { int pv = t + 1; CSTORE4(flags + idx, pv); }
}

// =====================================================================
// bf16 MFMA GEMM (verified r6/r12) — used for gi0 and the convs.
// =====================================================================
template<int AMODE, int OMODE>
__global__ __launch_bounds__(256) void gemm_mfma(
    const float* __restrict__ A, const unsigned short* __restrict__ Wb,
    const float* __restrict__ bias,
    unsigned short* __restrict__ Cb, unsigned int* __restrict__ pool,
    int N, int K, int ldA, int rowsPerB, int tilesPerB, int nb,
    const int* __restrict__ order, const int* __restrict__ nsel, int poolOff)
{
    __shared__ __align__(16) unsigned short As[64][40];
    __shared__ __align__(16) unsigned short Bs[64][40];
    __shared__ const float* rowp[64];

    const int tid = threadIdx.x;
    const int l = tid & 63;
    const int q = tid >> 6;
    const int per = 16 * nb;
    const int id = blockIdx.x;
    const int sup = id / per, rr2 = id % per;
    const int mblk = sup * 16 + (rr2 & 15);
    const int n0 = (rr2 >> 4) * 64;

    int tileb = 0, tilet0 = 0;
    if (AMODE != 0) { tileb = mblk / tilesPerB; tilet0 = (mblk % tilesPerB) * 64; }

    if (tid < 64) {
        const float* p = nullptr;
        if (AMODE == 0) {
            p = A + ((size_t)mblk * 64 + tid) * (size_t)ldA;
        } else if (AMODE == 1) {
            int t = tilet0 + tid;
            if (t < nsel[tileb]) {
                int src = order[tileb * T_ + t];
                p = A + ((size_t)tileb * T_ + src) * (size_t)ldA;
            }
        } else {
            int t = tilet0 + tid;
            if (t < rowsPerB) p = A + ((size_t)tileb * T_ + t) * (size_t)ldA;
        }
        rowp[tid] = p;
    }
    __syncthreads();

    f32x4 acc0 = {0.f,0.f,0.f,0.f}, acc1 = {0.f,0.f,0.f,0.f};
    f32x4 acc2 = {0.f,0.f,0.f,0.f}, acc3 = {0.f,0.f,0.f,0.f};

    const int r = tid & 63, seg = tid >> 6;
    const float* ap = rowp[r];
    if (ap) ap += seg * 8;
    const unsigned short* wrow = Wb + (size_t)(n0 + r) * (size_t)K + seg * 8;

    for (int k0 = 0; k0 < K; k0 += 32) {
        float4 fa = make_float4(0,0,0,0), fb = make_float4(0,0,0,0);
        if (ap) { fa = *(const float4*)(ap + k0); fb = *(const float4*)(ap + k0 + 4); }
        const uint4 wv = *(const uint4*)(wrow + k0);
        __syncthreads();
        uint4 pk;
        pk.x = (unsigned)f2bu(fa.x) | ((unsigned)f2bu(fa.y) << 16);
        pk.y = (unsigned)f2bu(fa.z) | ((unsigned)f2bu(fa.w) << 16);
        pk.z = (unsigned)f2bu(fb.x) | ((unsigned)f2bu(fb.y) << 16);
        pk.w = (unsigned)f2bu(fb.z) | ((unsigned)f2bu(fb.w) << 16);
        *(uint4*)&As[r][seg * 8] = pk;
        *(uint4*)&Bs[r][seg * 8] = wv;
        __syncthreads();
        const bf16x8 av = *(const bf16x8*)&As[q * 16 + (l & 15)][(l >> 4) * 8];
        const bf16x8 b0 = *(const bf16x8*)&Bs[ 0 + (l & 15)][(l >> 4) * 8];
        const bf16x8 b1 = *(const bf16x8*)&Bs[16 + (l & 15)][(l >> 4) * 8];
        const bf16x8 b2 = *(const bf16x8*)&Bs[32 + (l & 15)][(l >> 4) * 8];
        const bf16x8 b3 = *(const bf16x8*)&Bs[48 + (l & 15)][(l >> 4) * 8];
        acc0 = __builtin_amdgcn_mfma_f32_16x16x32_bf16(av, b0, acc0, 0, 0, 0);
        acc1 = __builtin_amdgcn_mfma_f32_16x16x32_bf16(av, b1, acc1, 0, 0, 0);
        acc2 = __builtin_amdgcn_mfma_f32_16x16x32_bf16(av, b2, acc2, 0, 0, 0);
        acc3 = __builtin_amdgcn_mfma_f32_16x16x32_bf16(av, b3, acc3, 0, 0, 0);
    }

    f32x4 accs[4] = {acc0, acc1, acc2, acc3};
    if (OMODE == 0) {
        const int mbase = (AMODE == 0) ? mblk * 64 : tileb * T_ + tilet0;
        #pragma unroll
        for (int s = 0; s < 4; ++s) {
            const int col = n0 + s * 16 + (l & 15);
            const float bv = bias[col];
            #pragma unroll
            for (int reg = 0; reg < 4; ++reg) {
                const int m = mbase + q * 16 + (l >> 4) * 4 + reg;
                Cb[(size_t)m * (size_t)N + col] = f2bu(accs[s][reg] + bv);
            }
        }
    } else {
        #pragma unroll
        for (int s = 0; s < 4; ++s) {
            const int col = n0 + s * 16 + (l & 15);
            const float bv = bias[col];
            float mx = 0.f;
            #pragma unroll
            for (int reg = 0; reg < 4; ++reg) {
                const int t = tilet0 + q * 16 + (l >> 4) * 4 + reg;
                const float val = fmaxf(accs[s][reg] + bv, 0.f);
                if (t < rowsPerB) mx = fmaxf(mx, val);
            }
            mx = fmaxf(mx, __shfl_xor(mx, 16));
            mx = fmaxf(mx, __shfl_xor(mx, 32));
            if (l < 16)
                atomicMax(&pool[(size_t)tileb * (3*NF_) + poolOff + n0 + s*16 + l],
                          __float_as_uint(mx));
        }
    }
}

// =====================================================================
// Merged weight f32 -> bf16 prep (verified r12).
// =====================================================================
__global__ void wprep_all(
    const float* __restrict__ w0, const float* __restrict__ w1,
    const float* __restrict__ w2, const float* __restrict__ w3,
    const float* __restrict__ w4, const float* __restrict__ w5,
    const float* __restrict__ w6, unsigned short* __restrict__ o)
{
    const int i = blockIdx.x * 256 + threadIdx.x;
    if (i >= WP_N6) return;
    float v;
    if      (i < WP_N0) v = w0[i];
    else if (i < WP_N1) v = w1[i - WP_N0];
    else if (i < WP_N2) v = w2[i - WP_N1];
    else if (i < WP_N3) v = w3[i - WP_N2];
    else if (i < WP_N4) v = w4[i - WP_N3];
    else if (i < WP_N5) v = w5[i - WP_N4];
    else                v = w6[i - WP_N5];
    o[i] = f2bu(v);
}

// =====================================================================
// Fused gi_c producer + selector GRU consumer (verified r15). 256 WGs.
// Producers front-load ALL gi_c then go idle -> quiet fabric for the
// latency-bound consumer (r16 lesson: stretching producer activity
// across the recurrence costs more in contention than it saves).
// =====================================================================
__device__ __forceinline__ void gates_abs(
    const float* __restrict__ hs, int b, int base,
    const float* __restrict__ wR, const float* __restrict__ wZ,
    const float* __restrict__ wN,
    float& aR, float& aZ, float& aN)
{
    #pragma unroll 4
    for (int kq = 0; kq < 32; ++kq) {
        const int k = base + kq * 4;
        const float hv0 = hs[(k+0)*64 + b];
        const float hv1 = hs[(k+1)*64 + b];
        const float hv2 = hs[(k+2)*64 + b];
        const float hv3 = hs[(k+3)*64 + b];
        const float4 wr = *(const float4*)(wR + k);
        const float4 wz = *(const float4*)(wZ + k);
        const float4 wn = *(const float4*)(wN + k);
        aR = fmaf(hv0, wr.x, aR); aR = fmaf(hv1, wr.y, aR);
        aR = fmaf(hv2, wr.z, aR); aR = fmaf(hv3, wr.w, aR);
        aZ = fmaf(hv0, wz.x, aZ); aZ = fmaf(hv1, wz.y, aZ);
        aZ = fmaf(hv2, wz.z, aZ); aZ = fmaf(hv3, wz.w, aZ);
        aN = fmaf(hv0, wn.x, aN); aN = fmaf(hv1, wn.y, aN);
        aN = fmaf(hv2, wn.z, aN); aN = fmaf(hv3, wn.w, aN);
    }
}

__device__ __forceinline__ void dot_abs(
    const float* __restrict__ hs, int b, int base,
    const float* __restrict__ dWl, float& dot)
{
    #pragma unroll 4
    for (int kq = 0; kq < 16; ++kq) {
        const int k = base + kq * 4;
        const float hv0 = hs[(k+0)*64 + b];
        const float hv1 = hs[(k+1)*64 + b];
        const float hv2 = hs[(k+2)*64 + b];
        const float hv3 = hs[(k+3)*64 + b];
        const float4 dv = *(const float4*)(dWl + k);
        dot = fmaf(hv0, dv.x, dot); dot = fmaf(hv1, dv.y, dot);
        dot = fmaf(hv2, dv.z, dot); dot = fmaf(hv3, dv.w, dot);
    }
}

__global__ __launch_bounds__(512) void sel_fused(
    const float* __restrict__ emb, const float* __restrict__ Wih_c,
    const float* __restrict__ bih_c, float* __restrict__ giC,
    const float* __restrict__ Whh, const float* __restrict__ bhh,
    const float* __restrict__ Ws, const float* __restrict__ bs,
    float* __restrict__ h0, float* __restrict__ h1,
    unsigned long long* __restrict__ selm, int* __restrict__ flags,
    int* __restrict__ jobs)
{
    __shared__ __align__(16) char smem[162816];   // union: consumer 159KB / producer 8.7KB
    const int tid = threadIdx.x;
    const int bx = blockIdx.x;

    if (bx >= 128) {
        // ------------------- PRODUCER: gi_c GEMM, chunk-ordered -------------------
        const int p = bx - 128;
        float* As = (float*)smem;            // [16][68]
        float* Bs = As + 16 * 68;
        const int half = tid >> 8;           // 0 = A stager, 1 = B stager
        const int t2 = tid & 255;
        const int srl = t2 >> 2, skl = (t2 & 3) * 4;
        const int ty = tid >> 4;             // 0..31 (2 rows)
        const int tx = tid & 15;             // 0..15 (4 cols)

        for (int c = 0; c < 8; ++c) {
            for (int j = p; j < 1536; j += 128) {
                const int b = j / 24, n = j % 24;
                const int mblk = b * 8 + c;
                const int n0 = n * 64;
                const float* src = (half == 0)
                    ? emb + ((size_t)mblk * 64 + srl) * (size_t)E_ + skl
                    : Wih_c + ((size_t)(n0 + srl)) * (size_t)E_ + skl;
                float* dl = (half == 0) ? As : Bs;

                float acc[2][4] = {};
                for (int k0 = 0; k0 < E_; k0 += 16) {
                    const float4 v = *(const float4*)(src + k0);
                    __syncthreads();
                    dl[(skl+0)*68 + srl] = v.x; dl[(skl+1)*68 + srl] = v.y;
                    dl[(skl+2)*68 + srl] = v.z; dl[(skl+3)*68 + srl] = v.w;
                    __syncthreads();
                    #pragma unroll
                    for (int kk = 0; kk < 16; ++kk) {
                        const float a0 = As[kk*68 + ty*2 + 0];
                        const float a1 = As[kk*68 + ty*2 + 1];
                        const float4 w4 = *(const float4*)&Bs[kk*68 + tx*4];
                        acc[0][0]=fmaf(a0,w4.x,acc[0][0]); acc[0][1]=fmaf(a0,w4.y,acc[0][1]);
                        acc[0][2]=fmaf(a0,w4.z,acc[0][2]); acc[0][3]=fmaf(a0,w4.w,acc[0][3]);
                        acc[1][0]=fmaf(a1,w4.x,acc[1][0]); acc[1][1]=fmaf(a1,w4.y,acc[1][1]);
                        acc[1][2]=fmaf(a1,w4.z,acc[1][2]); acc[1][3]=fmaf(a1,w4.w,acc[1][3]);
                    }
                }
                const float4 bv = *(const float4*)(bih_c + n0 + tx*4);
                f32x4 o0, o1;   // ext_vector_type for asm store
                o0[0] = acc[0][0]+bv.x; o0[1] = acc[0][1]+bv.y;
                o0[2] = acc[0][2]+bv.z; o0[3] = acc[0][3]+bv.w;
                o1[0] = acc[1][0]+bv.x; o1[1] = acc[1][1]+bv.y;
                o1[2] = acc[1][2]+bv.z; o1[3] = acc[1][3]+bv.w;
                const float* d0 = giC + (size_t)(mblk * 64 + ty*2) * (size_t)G_ + n0 + tx*4;
                CSTOREX4(d0, o0);
                CSTOREX4(d0 + G_, o1);
                asm volatile("s_waitcnt vmcnt(0)" ::: "memory");
                __syncthreads();
                if (tid == 0)
                    __hip_atomic_fetch_add(jobs + c, 1, __ATOMIC_RELAXED,
                                           __HIP_MEMORY_SCOPE_AGENT);
                __syncthreads();
            }
        }
        return;
    }

    // ------------------- CONSUMER: rec_sel v7 -------------------
    float* Wl    = (float*)smem;           // 6144
    float* dWl   = Wl + 6144;              // 512
    float* hs    = dWl + 512;              // 32768
    float* partR = hs + 32768;             // 256
    float* partZ = partR + 256;            // 256
    float* partN = partZ + 256;            // 256
    float* pdot  = partN + 256;            // 512

    const int b = tid & 63;
    const int w = __builtin_amdgcn_readfirstlane(tid >> 6);
    const int u = w >> 1, s = w & 1;
    const int iu = bx * 4 + u;

    for (int idx = tid; idx < 12 * 512; idx += 512) {
        int rr = idx >> 9, k = idx & 511;
        int ul = rr / 3, gate = rr - ul * 3;
        Wl[idx] = Whh[((size_t)gate * 512 + bx * 4 + ul) * 512 + k];
    }
    dWl[tid] = Ws[512 + tid] - Ws[tid];
    __syncthreads();

    const float bR = bhh[iu], bZ = bhh[512 + iu], bN = bhh[1024 + iu];
    const float db = bs[1] - bs[0];
    const float* __restrict__ wR = Wl + (u*3 + 0) * 512;
    const float* __restrict__ wZ = Wl + (u*3 + 1) * 512;
    const float* __restrict__ wN = Wl + (u*3 + 2) * 512;

    // gi(t=0) prefetch — gated on chunk 0, coherent
    float pgR = 0.f, pgZ = 0.f, pgN = 0.f;
    int ready_chunk = 0;
    if (s == 0) {
        poll_cnt(jobs + 0, 1536);
        ready_chunk = 1;
        const float* gp = giC + (size_t)b * T_ * G_;
        asm volatile("global_load_dword %0, %3, off sc0 sc1\n\t"
                     "global_load_dword %1, %4, off sc0 sc1\n\t"
                     "global_load_dword %2, %5, off sc0 sc1\n\t"
                     "s_waitcnt vmcnt(0)"
                     : "=&v"(pgR), "=&v"(pgZ), "=&v"(pgN)
                     : "v"(gp + iu), "v"(gp + 512 + iu), "v"(gp + 1024 + iu)
                     : "memory");
    }

    for (int t = 0; t <= T_; ++t) {
        const bool comp = (t < T_);
        const float* hcur = (t & 1) ? h1 : h0;
        float* hnxt = (t & 1) ? h0 : h1;

        if (t > 0) bar_wait128(flags, t, tid);

        // ---- single-shot stage of full h(t): 16 CLOAD4/thread ----
        const float* hc = hcur + (size_t)tid * 4;
        float* hd = hs + tid * 4;
        float4 a0,a1,a2,a3,a4,a5,a6,a7,a8,a9,aa,ab,ac,ad,ae,af;
        CLOAD4(a0, hc +  0*2048); CLOAD4(a1, hc +  1*2048);
        CLOAD4(a2, hc +  2*2048); CLOAD4(a3, hc +  3*2048);
        CLOAD4(a4, hc +  4*2048); CLOAD4(a5, hc +  5*2048);
        CLOAD4(a6, hc +  6*2048); CLOAD4(a7, hc +  7*2048);
        CLOAD4(a8, hc +  8*2048); CLOAD4(a9, hc +  9*2048);
        CLOAD4(aa, hc + 10*2048); CLOAD4(ab, hc + 11*2048);
        CLOAD4(ac, hc + 12*2048); CLOAD4(ad, hc + 13*2048);
        CLOAD4(ae, hc + 14*2048); CLOAD4(af, hc + 15*2048);
        CWAIT();
        *(float4*)(hd +  0*2048) = a0; *(float4*)(hd +  1*2048) = a1;
        *(float4*)(hd +  2*2048) = a2; *(float4*)(hd +  3*2048) = a3;
        *(float4*)(hd +  4*2048) = a4; *(float4*)(hd +  5*2048) = a5;
        *(float4*)(hd +  6*2048) = a6; *(float4*)(hd +  7*2048) = a7;
        *(float4*)(hd +  8*2048) = a8; *(float4*)(hd +  9*2048) = a9;
        *(float4*)(hd + 10*2048) = aa; *(float4*)(hd + 11*2048) = ab;
        *(float4*)(hd + 12*2048) = ac; *(float4*)(hd + 13*2048) = ad;
        *(float4*)(hd + 14*2048) = ae; *(float4*)(hd + 15*2048) = af;
        __syncthreads();

        float aR = (s == 0) ? bR : 0.f;
        float aZ = (s == 0) ? bZ : 0.f;
        float aN = (s == 0) ? bN : 0.f;
        float dot = 0.f, hp = 0.f;

        if (comp) {
            gates_abs(hs, b, s * 128,       wR, wZ, wN, aR, aZ, aN);
            gates_abs(hs, b, 256 + s * 128, wR, wZ, wN, aR, aZ, aN);
            if (s == 0) hp = hs[iu * 64 + b];
        }
        dot_abs(hs, b, (w < 4) ? w * 64 : 256 + (w - 4) * 64, dWl, dot);

        if (comp && s == 1) {
            partR[u*64 + b] = aR; partZ[u*64 + b] = aZ; partN[u*64 + b] = aN;
        }
        pdot[w*64 + b] = dot;
        __syncthreads();

        if (comp && s == 0) {
            aR += partR[u*64 + b]; aZ += partZ[u*64 + b]; aN += partN[u*64 + b];
            const float r = sigm(pgR + aR);
            const float z = sigm(pgZ + aZ);
            const float n = tanhf(pgN + r * aN);
            const float hn = (1.f - z) * n + z * hp;
            const float* hdst = hnxt + (size_t)iu * 64 + b;
            CSTORE4(hdst, hn);
        }

        if (t < T_) {
            bar_arrive(flags, t, tid, bx);
            // gi(t+1) prefetch after flag store; gated on producer chunk
            if (s == 0 && t + 1 < T_) {
                const int nc = (t + 1) >> 6;
                if (nc >= ready_chunk) { poll_cnt(jobs + nc, 1536); ready_chunk = nc + 1; }
                const float* gp = giC + ((size_t)b * T_ + t + 1) * G_;
                asm volatile("global_load_dword %0, %3, off sc0 sc1\n\t"
                             "global_load_dword %1, %4, off sc0 sc1\n\t"
                             "global_load_dword %2, %5, off sc0 sc1\n\t"
                             "s_waitcnt vmcnt(0)"
                             : "=&v"(pgR), "=&v"(pgZ), "=&v"(pgN)
                             : "v"(gp + iu), "v"(gp + 512 + iu), "v"(gp + 1024 + iu)
                             : "memory");
            }
        }
        if (w == 0 && t >= 1) {
            float p2 = pdot[0*64 + b];
            p2 += pdot[1*64 + b]; p2 += pdot[2*64 + b]; p2 += pdot[3*64 + b];
            p2 += pdot[4*64 + b]; p2 += pdot[5*64 + b]; p2 += pdot[6*64 + b];
            p2 += pdot[7*64 + b];
            unsigned long long m = __ballot((p2 + db) > 0.f);
            if (tid == 0 && bx == 0) selm[t - 1] = m;
        }
    }
}

// =====================================================================
// FUSED layer0 -> gi1 -> layer1 pipeline (verified r13/r15, unchanged).
// =====================================================================
template<int ROLE>
__device__ __forceinline__ void layer_body(
    int wg, int tid,
    const unsigned short* __restrict__ gi0,
    const unsigned short* __restrict__ ring1,
    unsigned short* __restrict__ ring0,
    const unsigned short* __restrict__ wbf, const float* __restrict__ bhh,
    const int* __restrict__ nselp, const int* __restrict__ maxnp,
    unsigned short* __restrict__ hA, unsigned short* __restrict__ hB,
    float* __restrict__ outp,
    int* __restrict__ flagsSelf, const int* __restrict__ flagsB,
    unsigned char* ldsW, unsigned char* ldsH, float* gbuf)
{
    const int l = tid & 63;
    const int q = tid >> 6;
    const int i0 = wg * 16;
    const int b = tid & 63;

    for (int idx = tid; idx < 48 * 64; idx += 256) {
        const int r = idx >> 6, seg = idx & 63;
        const int tier = r >> 4, ul = r & 15;
        const float4 v = *(const float4*)((const char*)wbf
            + ((size_t)(tier * 512 + i0 + ul) * 512) * 2 + seg * 16);
        *(float4*)(ldsW + r * 1040 + seg * 16) = v;
    }
    const float4 bRv = *(const float4*)(bhh + i0 + 4 * q);
    const float4 bZv = *(const float4*)(bhh + 512 + i0 + 4 * q);
    const float4 bNv = *(const float4*)(bhh + 1024 + i0 + 4 * q);
    const int ns = nselp[b];
    const int TOTAL = *maxnp;

    const unsigned short* gbase = gi0 + (size_t)b * T_ * (size_t)G_ + i0 + 4 * q;
    uint2 gR, gZ, gN;
    if (ROLE == 0) {
        gR = *(const uint2*)(gbase);
        gZ = *(const uint2*)(gbase + 512);
        gN = *(const uint2*)(gbase + 1024);
    }
    __syncthreads();

    for (int t = 0; t < TOTAL; ++t) {
        const unsigned short* hcur = (t & 1) ? hB : hA;
        unsigned short* hnxt = (t & 1) ? hA : hB;

        if (t > 0) bar_wait<32>(flagsSelf, t, tid);
        if (ROLE == 0) {
            if (t >= 4) poll_ge<24>(flagsB, t - 3, tid);
        } else {
            poll_ge<24>(flagsB, t + 1, tid);
            const unsigned short* gp = ring1 + ((size_t)(t & 3) * 64 + b) * G_ + i0 + 4 * q;
            CLOAD2(gR, gp); CLOAD2(gZ, gp + 512); CLOAD2(gN, gp + 1024);
        }

        {
            const char* src = (const char*)hcur + tid * 256;
            float4 s0, s1, s2, s3, s4, s5, s6, s7, s8, s9, sa, sb_, sc, sd, se, sf;
            CLOAD4(s0, src + 0 * 16);  CLOAD4(s1, src + 1 * 16);
            CLOAD4(s2, src + 2 * 16);  CLOAD4(s3, src + 3 * 16);
            CLOAD4(s4, src + 4 * 16);  CLOAD4(s5, src + 5 * 16);
            CLOAD4(s6, src + 6 * 16);  CLOAD4(s7, src + 7 * 16);
            CLOAD4(s8, src + 8 * 16);  CLOAD4(s9, src + 9 * 16);
            CLOAD4(sa, src + 10 * 16); CLOAD4(sb_, src + 11 * 16);
            CLOAD4(sc, src + 12 * 16); CLOAD4(sd, src + 13 * 16);
            CLOAD4(se, src + 14 * 16); CLOAD4(sf, src + 15 * 16);
            CWAIT();
            char* dst = (char*)ldsH + (tid >> 2) * 1040 + (tid & 3) * 256;
            *(float4*)(dst + 0 * 16) = s0;  *(float4*)(dst + 1 * 16) = s1;
            *(float4*)(dst + 2 * 16) = s2;  *(float4*)(dst + 3 * 16) = s3;
            *(float4*)(dst + 4 * 16) = s4;  *(float4*)(dst + 5 * 16) = s5;
            *(float4*)(dst + 6 * 16) = s6;  *(float4*)(dst + 7 * 16) = s7;
            *(float4*)(dst + 8 * 16) = s8;  *(float4*)(dst + 9 * 16) = s9;
            *(float4*)(dst + 10 * 16) = sa; *(float4*)(dst + 11 * 16) = sb_;
            *(float4*)(dst + 12 * 16) = sc; *(float4*)(dst + 13 * 16) = sd;
            *(float4*)(dst + 14 * 16) = se; *(float4*)(dst + 15 * 16) = sf;
        }
        __syncthreads();

        f32x4 ac0 = {0.f, 0.f, 0.f, 0.f};
        f32x4 ac1 = {0.f, 0.f, 0.f, 0.f};
        f32x4 ac2 = {0.f, 0.f, 0.f, 0.f};
        {
            const char* ab2 = (const char*)ldsH + (q * 16 + (l & 15)) * 1040 + (l >> 4) * 16;
            const char* bb = (const char*)ldsW + (l & 15) * 1040 + (l >> 4) * 16;
            #pragma unroll
            for (int ks = 0; ks < 16; ++ks) {
                const bf16x8 av = *(const bf16x8*)(ab2 + ks * 64);
                const bf16x8 w0 = *(const bf16x8*)(bb + ks * 64);
                const bf16x8 w1 = *(const bf16x8*)(bb + 16 * 1040 + ks * 64);
                const bf16x8 w2 = *(const bf16x8*)(bb + 32 * 1040 + ks * 64);
                ac0 = __builtin_amdgcn_mfma_f32_16x16x32_bf16(av, w0, ac0, 0, 0, 0);
                ac1 = __builtin_amdgcn_mfma_f32_16x16x32_bf16(av, w1, ac1, 0, 0, 0);
                ac2 = __builtin_amdgcn_mfma_f32_16x16x32_bf16(av, w2, ac2, 0, 0, 0);
            }
        }
        {
            const int gcol = q * 16 + 4 * (l >> 4);
            const int grow = l & 15;
            #pragma unroll
            for (int r = 0; r < 4; ++r) {
                gbuf[grow * 66 + gcol + r]        = ac0[r];
                gbuf[(16 + grow) * 66 + gcol + r] = ac1[r];
                gbuf[(32 + grow) * 66 + gcol + r] = ac2[r];
            }
        }
        __syncthreads();

        {
            const ushort4 hp4 = *(const ushort4*)((const char*)ldsH
                                 + b * 1040 + (i0 + 4 * q) * 2);
            const unsigned short hpb[4] = {hp4.x, hp4.y, hp4.z, hp4.w};
            const float irv[4] = {b2f(gR.x & 0xffff), b2f(gR.x >> 16),
                                  b2f(gR.y & 0xffff), b2f(gR.y >> 16)};
            const float izv[4] = {b2f(gZ.x & 0xffff), b2f(gZ.x >> 16),
                                  b2f(gZ.y & 0xffff), b2f(gZ.y >> 16)};
            const float inv[4] = {b2f(gN.x & 0xffff), b2f(gN.x >> 16),
                                  b2f(gN.y & 0xffff), b2f(gN.y >> 16)};
            float4 o;
            unsigned short ob[4];
            #pragma unroll
            for (int j = 0; j < 4; ++j) {
                const int u2 = 4 * q + j;
                const float hr = gbuf[u2 * 66 + b]        + bRv[j];
                const float hz = gbuf[(16 + u2) * 66 + b] + bZv[j];
                const float hn = gbuf[(32 + u2) * 66 + b] + bNv[j];
                const float rr = sigm(irv[j] + hr);
                const float zz = sigm(izv[j] + hz);
                const float nn = tanhf(inv[j] + rr * hn);
                const float hpf = b2f(hpb[j]);
                float hv = (1.f - zz) * nn + zz * hpf;
                if (t >= ns) hv = hpf;
                ((float*)&o)[j] = hv;
                ob[j] = f2bu(hv);
            }
            uint2 hpk;
            hpk.x = (unsigned)ob[0] | ((unsigned)ob[1] << 16);
            hpk.y = (unsigned)ob[2] | ((unsigned)ob[3] << 16);
            if (ROLE == 0) {
                const unsigned short* rdst = ring0 + ((size_t)(t & 3) * 64 + b) * 512 + i0 + 4 * q;
                CSTORE8(rdst, hpk);
            } else {
                if (t < ns)
                    *(float4*)(outp + ((size_t)b * T_ + t) * 512 + i0 + 4 * q) = o;
            }
            const unsigned short* hdst = hnxt + (size_t)b * 512 + i0 + 4 * q;
            CSTORE8(hdst, hpk);
        }

        bar_arrive(flagsSelf, t, tid, wg);
        if (ROLE == 0 && t + 1 < TOTAL) {
            const unsigned short* gp = gbase + (size_t)(t + 1) * G_;
            gR = *(const uint2*)gp;
            gZ = *(const uint2*)(gp + 512);
            gN = *(const uint2*)(gp + 1024);
        }
    }
}

__global__ __launch_bounds__(256) void rec_fused(
    const unsigned short* __restrict__ gi0,
    const unsigned short* __restrict__ wbf0,
    const unsigned short* __restrict__ wbf1,
    const unsigned short* __restrict__ wih1b,
    const float* __restrict__ bhh0, const float* __restrict__ bhh1,
    const float* __restrict__ bih1,
    const int* __restrict__ nselp, const int* __restrict__ maxnp,
    unsigned short* __restrict__ h0A, unsigned short* __restrict__ h1A,
    unsigned short* __restrict__ h0C, unsigned short* __restrict__ h1C,
    unsigned short* __restrict__ ring0, unsigned short* __restrict__ ring1,
    float* __restrict__ outp,
    int* __restrict__ flagsA, int* __restrict__ flagsB, int* __restrict__ flagsC)
{
    __shared__ __align__(16) unsigned char ldsX[64 * 1040];
    __shared__ __align__(16) unsigned char ldsY[64 * 1040];
    __shared__ float gbuf[48 * 66];

    const int tid = threadIdx.x;
    const int bx = blockIdx.x;

    if (bx < 32) {
        layer_body<0>(bx, tid, gi0, nullptr, ring0, wbf0, bhh0, nselp, maxnp,
                      h0A, h1A, nullptr, flagsA, flagsB, ldsX, ldsY, gbuf);
    } else if (bx < 56) {
        const int wg = bx - 32;
        const int l = tid & 63;
        const int q = tid >> 6;
        const int n0 = wg * 64;

        for (int idx = tid; idx < 64 * 64; idx += 256) {
            const int r = idx >> 6, seg = idx & 63;
            const float4 v = *(const float4*)((const char*)wih1b
                + ((size_t)(n0 + r) * 512) * 2 + seg * 16);
            *(float4*)(ldsX + r * 1040 + seg * 16) = v;
        }
        float bv[4];
        #pragma unroll
        for (int s = 0; s < 4; ++s) bv[s] = bih1[n0 + s * 16 + (l & 15)];
        const int TOTAL = *maxnp;
        __syncthreads();

        for (int t = 0; t < TOTAL; ++t) {
            poll_ge<32>(flagsA, t + 1, tid);
            if (t >= 4) poll_ge<32>(flagsC, t - 3, tid);

            {
                const char* src = (const char*)ring0 + (size_t)(t & 3) * 65536 + tid * 256;
                float4 s0, s1, s2, s3, s4, s5, s6, s7, s8, s9, sa, sb_, sc, sd, se, sf;
                CLOAD4(s0, src + 0 * 16);  CLOAD4(s1, src + 1 * 16);
                CLOAD4(s2, src + 2 * 16);  CLOAD4(s3, src + 3 * 16);
                CLOAD4(s4, src + 4 * 16);  CLOAD4(s5, src + 5 * 16);
                CLOAD4(s6, src + 6 * 16);  CLOAD4(s7, src + 7 * 16);
                CLOAD4(s8, src + 8 * 16);  CLOAD4(s9, src + 9 * 16);
                CLOAD4(sa, src + 10 * 16); CLOAD4(sb_, src + 11 * 16);
                CLOAD4(sc, src + 12 * 16); CLOAD4(sd, src + 13 * 16);
                CLOAD4(se, src + 14 * 16); CLOAD4(sf, src + 15 * 16);
                CWAIT();
                char* dst = (char*)ldsY + (tid >> 2) * 1040 + (tid & 3) * 256;
                *(float4*)(dst + 0 * 16) = s0;  *(float4*)(dst + 1 * 16) = s1;
                *(float4*)(dst + 2 * 16) = s2;  *(float4*)(dst + 3 * 16) = s3;
                *(float4*)(dst + 4 * 16) = s4;  *(float4*)(dst + 5 * 16) = s5;
                *(float4*)(dst + 6 * 16) = s6;  *(float4*)(dst + 7 * 16) = s7;
                *(float4*)(dst + 8 * 16) = s8;  *(float4*)(dst + 9 * 16) = s9;
                *(float4*)(dst + 10 * 16) = sa; *(float4*)(dst + 11 * 16) = sb_;
                *(float4*)(dst + 12 * 16) = sc; *(float4*)(dst + 13 * 16) = sd;
                *(float4*)(dst + 14 * 16) = se; *(float4*)(dst + 15 * 16) = sf;
            }
            __syncthreads();

            f32x4 acc0 = {0.f,0.f,0.f,0.f}, acc1 = {0.f,0.f,0.f,0.f};
            f32x4 acc2 = {0.f,0.f,0.f,0.f}, acc3 = {0.f,0.f,0.f,0.f};
            {
                const char* ab2 = (const char*)ldsY + (q * 16 + (l & 15)) * 1040 + (l >> 4) * 16;
                const char* bb = (const char*)ldsX + (l & 15) * 1040 + (l >> 4) * 16;
                #pragma unroll
                for (int ks = 0; ks < 16; ++ks) {
                    const bf16x8 av = *(const bf16x8*)(ab2 + ks * 64);
                    const bf16x8 b0 = *(const bf16x8*)(bb + ks * 64);
                    const bf16x8 b1 = *(const bf16x8*)(bb + 16 * 1040 + ks * 64);
                    const bf16x8 b2 = *(const bf16x8*)(bb + 32 * 1040 + ks * 64);
                    const bf16x8 b3 = *(const bf16x8*)(bb + 48 * 1040 + ks * 64);
                    acc0 = __builtin_amdgcn_mfma_f32_16x16x32_bf16(av, b0, acc0, 0, 0, 0);
                    acc1 = __builtin_amdgcn_mfma_f32_16x16x32_bf16(av, b1, acc1, 0, 0, 0);
                    acc2 = __builtin_amdgcn_mfma_f32_16x16x32_bf16(av, b2, acc2, 0, 0, 0);
                    acc3 = __builtin_amdgcn_mfma_f32_16x16x32_bf16(av, b3, acc3, 0, 0, 0);
                }
            }
            f32x4 accs[4] = {acc0, acc1, acc2, acc3};
            #pragma unroll
            for (int s = 0; s < 4; ++s) {
                const int col = n0 + s * 16 + (l & 15);
                #pragma unroll
                for (int reg = 0; reg < 4; ++reg) {
                    const int m = q * 16 + (l >> 4) * 4 + reg;
                    const unsigned val = f2bu(accs[s][reg] + bv[s]);
                    const unsigned short* dst = ring1 + ((size_t)(t & 3) * 64 + m) * G_ + col;
                    CSTORE2(dst, val);
                }
            }
            bar_arrive(flagsB, t, tid, wg);
        }
    } else {
        layer_body<1>(bx - 56, tid, nullptr, ring1, nullptr, wbf1, bhh1, nselp, maxnp,
                      h0C, h1C, outp, flagsC, flagsB, ldsX, ldsY, gbuf);
    }
}

// =====================================================================
// Per-batch selection post-processing (unchanged, selm version).
// =====================================================================
__global__ void build_order_k(const int* __restrict__ mask,
                              const unsigned long long* __restrict__ selm,
                              int* __restrict__ order, int* __restrict__ nsel,
                              int* __restrict__ maxn)
{
    const int b = threadIdx.x;
    int lens = 0;
    for (int t = 0; t < T_; ++t) lens += (mask[b * T_ + t] != 0);
    int cnt = 0;
    for (int t = 0; t < T_; ++t) {
        int s = (int)((selm[t] >> b) & 1ull);
        if (t == 0) s = 1;
        if (t == lens - 1) s = 1;
        if (t >= lens) s = 0;
        if (s) order[b * T_ + (cnt++)] = t;
    }
    nsel[b] = cnt;
    int c2 = cnt;
    for (int t = 0; t < T_; ++t) {
        int s = (int)((selm[t] >> b) & 1ull);
        if (t == 0) s = 1;
        if (t == lens - 1) s = 1;
        if (t >= lens) s = 0;
        if (!s) order[b * T_ + (c2++)] = t;
    }
    __shared__ int red[64];
    red[b] = cnt;
    __syncthreads();
    if (b == 0) {
        int m = 0;
        for (int qq = 0; qq < 64; ++qq) m = max(m, red[qq]);
        *maxn = m;
    }
}

// =====================================================================
// Final linear (unchanged).
// =====================================================================
__global__ void final_k(const unsigned int* __restrict__ pool,
                        const float* __restrict__ Wo, const float* __restrict__ bo,
                        float* __restrict__ out)
{
    const int b = threadIdx.x;
    float s = bo[0];
    for (int f = 0; f < 3 * NF_; ++f)
        s = fmaf(__uint_as_float(pool[b * (3*NF_) + f]), Wo[f], s);
    out[b] = s;
}

// =====================================================================
extern "C" void kernel_launch(void* const* d_in, const int* in_sizes, int n_in,
                              void* d_out, int out_size, void* d_ws, size_t ws_size,
                              hipStream_t stream)
{
    (void)in_sizes; (void)n_in; (void)out_size;
    const float* emb   = (const float*)d_in[0];
    const int*   mask  = (const int*)d_in[1];
    const float* Wih_c = (const float*)d_in[2];
    const float* Whh_c = (const float*)d_in[3];
    const float* bih_c = (const float*)d_in[4];
    const float* bhh_c = (const float*)d_in[5];
    const float* Ws    = (const float*)d_in[6];
    const float* bs    = (const float*)d_in[7];
    const float* Wih0  = (const float*)d_in[8];
    const float* Whh0  = (const float*)d_in[9];
    const float* bih0  = (const float*)d_in[10];
    const float* bhh0  = (const float*)d_in[11];
    const float* Wih1  = (const float*)d_in[12];
    const float* Whh1  = (const float*)d_in[13];
    const float* bih1  = (const float*)d_in[14];
    const float* bhh1  = (const float*)d_in[15];
    const float* Wc3   = (const float*)d_in[16];
    const float* bc3   = (const float*)d_in[17];
    const float* Wc4   = (const float*)d_in[18];
    const float* bc4   = (const float*)d_in[19];
    const float* Wc5   = (const float*)d_in[20];
    const float* bc5   = (const float*)d_in[21];
    const float* Wo    = (const float*)d_in[22];
    const float* bo    = (const float*)d_in[23];

    if (ws_size < WS_NEED) return;
    char* ws = (char*)d_ws;
    float*          giC    = (float*)(ws + OFF_GI);
    unsigned short* giB    = (unsigned short*)(ws + OFF_GI);
    float*          outbuf = (float*)(ws + OFF_OUT);
    unsigned short* wpack  = (unsigned short*)(ws + OFF_WBF0);
    unsigned short* wbf0   = (unsigned short*)(ws + OFF_WBF0);
    unsigned short* wbf1   = (unsigned short*)(ws + OFF_WBF1);
    unsigned short* wih0b  = (unsigned short*)(ws + OFF_WIH0);
    unsigned short* wih1b  = (unsigned short*)(ws + OFF_WIH1);
    unsigned short* wc3b   = (unsigned short*)(ws + OFF_WC3);
    unsigned short* wc4b   = (unsigned short*)(ws + OFF_WC4);
    unsigned short* wc5b   = (unsigned short*)(ws + OFF_WC5);
    float*          h0f    = (float*)(ws + OFF_H0);
    float*          h1f    = (float*)(ws + OFF_H1);
    unsigned short* h0A    = (unsigned short*)(ws + OFF_H0);
    unsigned short* h1A    = (unsigned short*)(ws + OFF_H0 + 65536);
    unsigned short* h0C    = (unsigned short*)(ws + OFF_H0 + 131072);
    unsigned short* h1C    = (unsigned short*)(ws + OFF_H0 + 196608);
    unsigned long long* selm = (unsigned long long*)(ws + OFF_SEL);
    int*            order  = (int*)(ws + OFF_ORD);
    int*            nsel   = (int*)(ws + OFF_NSEL);
    int*            maxn   = (int*)(ws + OFF_MAXN);
    int*            flagsA = (int*)(ws + OFF_FLG);
    int*            flagsB = (int*)(ws + OFF_FLG + 128);
    int*            flagsC = (int*)(ws + OFF_FLG + 256);
    int*            jobs   = (int*)(ws + OFF_JOBS);
    unsigned int*   pool   = (unsigned int*)(ws + OFF_POOL);
    unsigned short* ring0  = (unsigned short*)(ws + OFF_RING0);
    unsigned short* ring1  = (unsigned short*)(ws + OFF_RING1);

    // 1+2. fused gi_c producers + selector recurrence -> selm
    hipMemsetAsync(flagsA, 0, 1024, stream);   // sel flags + jobs counters
    hipMemsetAsync(h0f, 0, (size_t)B_ * H_ * 4, stream);
    sel_fused<<<256, 512, 0, stream>>>(emb, Wih_c, bih_c, giC, Whh_c, bhh_c,
                                       Ws, bs, h0f, h1f, selm, flagsA, jobs);
    // 3. forcing + stable partition
    build_order_k<<<1, 64, 0, stream>>>(mask, selm, order, nsel, maxn);
    // 3b. merged bf16 weight prep (after sel_fused; aliases gi_c tail)
    wprep_all<<<(WP_N6 + 255) / 256, 256, 0, stream>>>(Whh0, Whh1, Wih0, Wih1,
                                                       Wc3, Wc4, Wc5, wpack);
    // 4. gi0 = new_emb @ Wih0^T + bih0 (gathered rows, bf16 MFMA, supertile)
    gemm_mfma<1,0><<<dim3(512 * 24), 256, 0, stream>>>(emb, wih0b, bih0, giB, nullptr,
                                                       G_, E_, E_, T_, 8, 24, order, nsel, 0);
    // 5. FUSED layer0 -> gi1 -> layer1 pipeline (verified r13)
    hipMemsetAsync(flagsA, 0, 512, stream);
    hipMemsetAsync(h0A, 0, 65536, stream);
    hipMemsetAsync(h0C, 0, 65536, stream);
    hipMemsetAsync(outbuf, 0, (size_t)B_ * T_ * H_ * 4, stream);
    rec_fused<<<88, 256, 0, stream>>>(giB, wbf0, wbf1, wih1b, bhh0, bhh1, bih1,
                                      nsel, maxn, h0A, h1A, h0C, h1C,
                                      ring0, ring1, outbuf, flagsA, flagsB, flagsC);
    // 8. convs (bf16 MFMA sliding-window, supertile) + relu + time-max pooling
    hipMemsetAsync(pool, 0, (size_t)B_ * 3 * NF_ * 4, stream);
    gemm_mfma<2,1><<<dim3(512 * 4), 256, 0, stream>>>(outbuf, wc3b, bc3, nullptr, pool,
                                                      NF_, 3*H_, H_, 510, 8, 4, nullptr, nullptr, 0);
    gemm_mfma<2,1><<<dim3(512 * 4), 256, 0, stream>>>(outbuf, wc4b, bc4, nullptr, pool,
                                                      NF_, 4*H_, H_, 509, 8, 4, nullptr, nullptr, 256);
    gemm_mfma<2,1><<<dim3(512 * 4), 256, 0, stream>>>(outbuf, wc5b, bc5, nullptr, pool,
                                                      NF_, 5*H_, H_, 508, 8, 4, nullptr, nullptr, 512);
    // 9. final linear -> d_out (64 f32)
    final_k<<<1, 64, 0, stream>>>(pool, Wo, bo, (float*)d_out);
}